// Round 4
// baseline (93.429 us; speedup 1.0000x reference)
//
#include <hip/hip_runtime.h>
#include <hip/hip_bf16.h>
#include <math.h>

#define NROWS 8192
#define HALF_N 4096
#define KD 512
#define BM 256
#define BK 64
#define TEMP_INV 2.0f
#define NBLK32 32                 // NROWS / BM
#define NTRI 528                  // NBLK32*(NBLK32+1)/2
#define NKT 8                     // KD / BK

typedef __attribute__((ext_vector_type(8))) short bf16x8;
typedef __attribute__((ext_vector_type(4))) float f32x4;

__device__ __forceinline__ unsigned short f2bf(float f) {
    unsigned int u = __float_as_uint(f);
    u = (u + 0x7FFFu + ((u >> 16) & 1u)) >> 16;   // round-to-nearest-even
    return (unsigned short)u;
}

// Kernel 1: row-normalize f32 -> bf16, zero accumulators.
__global__ __launch_bounds__(256) void normalize_kernel(const float* __restrict__ X,
                                                        unsigned short* __restrict__ XN,
                                                        float* __restrict__ sumexp,
                                                        float* __restrict__ out) {
    const int row = blockIdx.x;
    const int tid = threadIdx.x;
    const int gz = row * 256 + tid;
    if (gz < NROWS) sumexp[gz] = 0.0f;
    if (gz == 0) out[0] = 0.0f;

    const float2 v = reinterpret_cast<const float2*>(X + (size_t)row * KD)[tid];
    float ss = v.x * v.x + v.y * v.y;
    #pragma unroll
    for (int off = 32; off >= 1; off >>= 1) ss += __shfl_xor(ss, off);
    __shared__ float wss[4];
    if ((tid & 63) == 0) wss[tid >> 6] = ss;
    __syncthreads();
    const float tot = wss[0] + wss[1] + wss[2] + wss[3];
    const float scale = 1.0f / fmaxf(sqrtf(tot), 1e-6f);
    ushort2 o;
    o.x = f2bf(v.x * scale);
    o.y = f2bf(v.y * scale);
    reinterpret_cast<ushort2*>(XN + (size_t)row * KD)[tid] = o;
}

// Stage one 16KB half-tile (2 x global_load_lds per thread). LDS dest is linear
// (wave-uniform base + lane*16); global source carries the inverse XOR swizzle
// (rule 21) matching the swizzled ds_read in the compute phases.
// A halves (isB=0): qhalf selects rows {q*64..q*64+63} U {128+q*64..128+q*64+63}.
// B halves (isB=1): qhalf selects rows with (row&63) in [q*32, q*32+32).
__device__ __forceinline__ void stage_half(const unsigned short* __restrict__ XN,
                                           int gRowBase, int kt, unsigned char* opBase,
                                           int qhalf, bool isB, int wid, int lane) {
    #pragma unroll
    for (int j = 0; j < 2; ++j) {
        const int b = wid * 2 + j;                    // 1KB block index 0..15
        const int rs = isB ? ((b >> 2) * 64 + qhalf * 32 + (b & 3) * 8)
                           : (qhalf * 64 + (b & 7) * 8 + (b >> 3) * 128);
        const int row = rs + (lane >> 3);
        const int c = lane & 7;
        const int sc = c ^ (row & 7);
        const unsigned short* g = XN + (size_t)(gRowBase + row) * KD + kt * BK + sc * 8;
        __builtin_amdgcn_global_load_lds((const __attribute__((address_space(1))) void*)g,
                                         (__attribute__((address_space(3))) void*)(opBase + row * 128 + c * 16),
                                         16, 0, 0);
    }
}

// One phase: 12 ds_read_b128 (quadrant QM,QN) | stage 1 half-tile | barrier |
// lgkmcnt(0) | setprio(1) 16 MFMA setprio(0) | [vmcnt tail] | barrier.
#define VMW asm volatile("s_waitcnt vmcnt(4)" ::: "memory"); __builtin_amdgcn_sched_barrier(0)
#define PHASE(As, Bs, QM, QN, STAGE, TAILVM) do {                              \
    bf16x8 aF[2][4], bF[2][2];                                                 \
    _Pragma("unroll")                                                          \
    for (int kk = 0; kk < 2; ++kk) {                                           \
      _Pragma("unroll")                                                        \
      for (int mm = 0; mm < 4; ++mm) {                                         \
        const int row = wr * 128 + ((QM) * 4 + mm) * 16 + l15;                 \
        const int sl  = (kk * 4 + l4) ^ (row & 7);                             \
        aF[kk][mm] = *(const bf16x8*)(As + row * 128 + sl * 16);               \
      }                                                                        \
      _Pragma("unroll")                                                        \
      for (int nn = 0; nn < 2; ++nn) {                                         \
        const int row = wc * 64 + ((QN) * 2 + nn) * 16 + l15;                  \
        const int sl  = (kk * 4 + l4) ^ (row & 7);                             \
        bF[kk][nn] = *(const bf16x8*)(Bs + row * 128 + sl * 16);               \
      }                                                                        \
    }                                                                          \
    STAGE;                                                                     \
    __builtin_amdgcn_s_barrier();                                              \
    asm volatile("s_waitcnt lgkmcnt(0)" ::: "memory");                         \
    __builtin_amdgcn_sched_barrier(0);                                         \
    __builtin_amdgcn_s_setprio(1);                                             \
    _Pragma("unroll")                                                          \
    for (int kk = 0; kk < 2; ++kk)                                             \
      _Pragma("unroll")                                                        \
      for (int mm = 0; mm < 4; ++mm)                                           \
        _Pragma("unroll")                                                      \
        for (int nn = 0; nn < 2; ++nn)                                         \
          acc[(QM) * 4 + mm][(QN) * 2 + nn] = __builtin_amdgcn_mfma_f32_16x16x32_bf16( \
              aF[kk][mm], bF[kk][nn], acc[(QM) * 4 + mm][(QN) * 2 + nn], 0, 0, 0);     \
    __builtin_amdgcn_s_setprio(0);                                             \
    TAILVM;                                                                    \
    __builtin_amdgcn_s_barrier();                                              \
    __builtin_amdgcn_sched_barrier(0);                                         \
  } while (0)

// Kernel 2: 256x256-tile 8-phase double-buffered GEMM (S = XN*XN^T), upper
// triangle only, fused exp + row/col sums + pos logits.
__global__ __launch_bounds__(512, 2) void gemm_fused_kernel(const unsigned short* __restrict__ XN,
                                                            float* __restrict__ sumexp,
                                                            float* __restrict__ poslogit) {
    __shared__ __align__(16) unsigned char lds[131072];   // slot0: A,B ; slot1: A,B

    // XCD swizzle (528 % 8 == 0) then triangular decode b -> (bi <= bj).
    const int b = (blockIdx.x & 7) * (NTRI / 8) + (blockIdx.x >> 3);
    int bi = (int)(32.5f - sqrtf(32.5f * 32.5f - 2.0f * (float)b));
    while ((bi + 1) * (65 - (bi + 1)) / 2 <= b) ++bi;
    while (bi * (65 - bi) / 2 > b) --bi;
    const int bj = bi + (b - bi * (65 - bi) / 2);

    const int rowBase = bi * BM;
    const int colBase = bj * BM;
    const bool offdiag = (bi != bj);

    const int tid  = threadIdx.x;
    const int lane = tid & 63;
    const int wid  = tid >> 6;         // 0..7
    const int wr   = wid >> 2;         // 0..1  (wave row: 128 output rows each)
    const int wc   = wid & 3;          // 0..3  (wave col: 64 output cols each)
    const int l15  = lane & 15;
    const int l4   = lane >> 4;

    unsigned char* A0 = lds;
    unsigned char* B0 = lds + 32768;
    unsigned char* A1 = lds + 65536;
    unsigned char* B1 = lds + 98304;

    f32x4 acc[8][4] = {};

    // Prologue: tile0 (4 halves) -> slot0; first 2 halves of tile1 -> slot1.
    stage_half(XN, colBase, 0, B0, 0, true , wid, lane);
    stage_half(XN, rowBase, 0, A0, 0, false, wid, lane);
    stage_half(XN, rowBase, 0, A0, 1, false, wid, lane);
    stage_half(XN, colBase, 0, B0, 1, true , wid, lane);
    stage_half(XN, colBase, 1, B1, 0, true , wid, lane);
    stage_half(XN, rowBase, 1, A1, 0, false, wid, lane);
    asm volatile("s_waitcnt vmcnt(4)" ::: "memory");       // tile0 fully landed
    __builtin_amdgcn_sched_barrier(0);
    __builtin_amdgcn_s_barrier();

    // Main loop: iteration i computes tiles 2i (slot0, ph1-4) and 2i+1 (slot1,
    // ph5-8); stages tile 2i+2 -> slot0 (ph3-6) and 2i+3 -> slot1 (ph7,8,then
    // ph1,2 of next iter). vmcnt(4) at ph4/ph8 = "2 half-tiles in flight".
    for (int i = 0; i < 4; ++i) {
        const int t1 = 2 * i + 1;
        const int t2 = (2 * i + 2 < NKT) ? 2 * i + 2 : NKT - 1;  // clamped source
        const int t3 = (2 * i + 3 < NKT) ? 2 * i + 3 : NKT - 1;  // (keeps ledger uniform)
        PHASE(A0, B0, 0, 0, stage_half(XN, rowBase, t1, A1, 1, false, wid, lane), );
        PHASE(A0, B0, 1, 0, stage_half(XN, colBase, t1, B1, 1, true , wid, lane), );
        PHASE(A0, B0, 0, 1, stage_half(XN, colBase, t2, B0, 0, true , wid, lane), );
        PHASE(A0, B0, 1, 1, stage_half(XN, rowBase, t2, A0, 0, false, wid, lane), VMW);
        PHASE(A1, B1, 0, 0, stage_half(XN, rowBase, t2, A0, 1, false, wid, lane), );
        PHASE(A1, B1, 1, 0, stage_half(XN, colBase, t2, B0, 1, true , wid, lane), );
        PHASE(A1, B1, 0, 1, stage_half(XN, colBase, t3, B1, 0, true , wid, lane), );
        PHASE(A1, B1, 1, 1, stage_half(XN, rowBase, t3, A1, 0, false, wid, lane), VMW);
    }

    // Drain everything (incl. clamped garbage stages) before LDS overlay.
    asm volatile("s_waitcnt vmcnt(0)" ::: "memory");
    __builtin_amdgcn_sched_barrier(0);
    __syncthreads();

    // Epilogue. C/D map: col = l15, row = l4*4 + reg.
    float* rowsum = (float*)lds;
    float* colsum = rowsum + BM;
    if (tid < BM) { rowsum[tid] = 0.0f; colsum[tid] = 0.0f; }
    __syncthreads();

    float cs[4] = {0.0f, 0.0f, 0.0f, 0.0f};
    #pragma unroll
    for (int m = 0; m < 8; ++m) {
        #pragma unroll
        for (int r = 0; r < 4; ++r) {
            const int row_l = wr * 128 + m * 16 + l4 * 4 + r;
            const int grow = rowBase + row_l;
            const int prow = grow < HALF_N ? grow + HALF_N : grow - HALF_N;
            float p = 0.0f;
            #pragma unroll
            for (int n = 0; n < 4; ++n) {
                const int gcol = colBase + wc * 64 + n * 16 + l15;
                const float s = acc[m][n][r] * TEMP_INV;
                const float e = (gcol != grow) ? __expf(s) : 0.0f;
                p += e;
                cs[n] += e;
                if (gcol == prow) {          // strictly upper triangle (bj = bi+16)
                    poslogit[grow] = s;
                    poslogit[gcol] = s;      // mirrored entry (pos involution)
                }
            }
            p += __shfl_xor(p, 1);
            p += __shfl_xor(p, 2);
            p += __shfl_xor(p, 4);
            p += __shfl_xor(p, 8);
            if (l15 == 0) atomicAdd(&rowsum[row_l], p);
        }
    }
    if (offdiag) {
        #pragma unroll
        for (int n = 0; n < 4; ++n) {
            float c = cs[n];
            c += __shfl_xor(c, 16);
            c += __shfl_xor(c, 32);
            if (l4 == 0) atomicAdd(&colsum[wc * 64 + n * 16 + l15], c);
        }
    }
    __syncthreads();
    if (tid < BM) {
        atomicAdd(&sumexp[rowBase + tid], rowsum[tid]);
        if (offdiag) atomicAdd(&sumexp[colBase + tid], colsum[tid]);
    }
}

// Kernel 3: loss = sum_i log(sumexp_i) - poslogit_i
__global__ __launch_bounds__(256) void finalize_kernel(const float* __restrict__ sumexp,
                                                       const float* __restrict__ poslogit,
                                                       float* __restrict__ out) {
    const int i = blockIdx.x * 256 + threadIdx.x;
    float li = logf(sumexp[i]) - poslogit[i];
    #pragma unroll
    for (int off = 32; off >= 1; off >>= 1) li += __shfl_xor(li, off);
    __shared__ float wss[4];
    if ((threadIdx.x & 63) == 0) wss[threadIdx.x >> 6] = li;
    __syncthreads();
    if (threadIdx.x == 0) atomicAdd(out, wss[0] + wss[1] + wss[2] + wss[3]);
}

extern "C" void kernel_launch(void* const* d_in, const int* in_sizes, int n_in,
                              void* d_out, int out_size, void* d_ws, size_t ws_size,
                              hipStream_t stream) {
    const float* X = (const float*)d_in[0];
    float* out = (float*)d_out;

    unsigned short* XN = (unsigned short*)d_ws;                       // 8 MB bf16
    float* sumexp   = (float*)((char*)d_ws + (size_t)NROWS * KD * 2); // 32 KB
    float* poslogit = sumexp + NROWS;                                 // 32 KB

    normalize_kernel<<<NROWS, 256, 0, stream>>>(X, XN, sumexp, out);
    gemm_fused_kernel<<<NTRI, 512, 0, stream>>>(XN, sumexp, poslogit);
    finalize_kernel<<<NROWS / 256, 256, 0, stream>>>(sumexp, poslogit, out);
}

// Round 5
// 92.626 us; speedup vs baseline: 1.0087x; 1.0087x over previous
//
#include <hip/hip_runtime.h>
#include <hip/hip_bf16.h>
#include <math.h>

#define NROWS 8192
#define HALF_N 4096
#define KD 512
#define BM 256
#define BK 64
#define TEMP_INV 2.0f
#define NBLK32 32                 // NROWS / BM
#define NTRI 528                  // NBLK32*(NBLK32+1)/2
#define NKT 8                     // KD / BK

typedef __attribute__((ext_vector_type(8))) short bf16x8;
typedef __attribute__((ext_vector_type(4))) float f32x4;

__device__ __forceinline__ unsigned short f2bf(float f) {
    unsigned int u = __float_as_uint(f);
    u = (u + 0x7FFFu + ((u >> 16) & 1u)) >> 16;   // round-to-nearest-even
    return (unsigned short)u;
}

// Kernel 1: row-normalize f32 -> bf16, zero accumulators.
__global__ __launch_bounds__(256) void normalize_kernel(const float* __restrict__ X,
                                                        unsigned short* __restrict__ XN,
                                                        float* __restrict__ sumexp,
                                                        float* __restrict__ out) {
    const int row = blockIdx.x;
    const int tid = threadIdx.x;
    const int gz = row * 256 + tid;
    if (gz < NROWS) sumexp[gz] = 0.0f;
    if (gz == 0) out[0] = 0.0f;

    const float2 v = reinterpret_cast<const float2*>(X + (size_t)row * KD)[tid];
    float ss = v.x * v.x + v.y * v.y;
    #pragma unroll
    for (int off = 32; off >= 1; off >>= 1) ss += __shfl_xor(ss, off);
    __shared__ float wss[4];
    if ((tid & 63) == 0) wss[tid >> 6] = ss;
    __syncthreads();
    const float tot = wss[0] + wss[1] + wss[2] + wss[3];
    const float scale = 1.0f / fmaxf(sqrtf(tot), 1e-6f);
    ushort2 o;
    o.x = f2bf(v.x * scale);
    o.y = f2bf(v.y * scale);
    reinterpret_cast<ushort2*>(XN + (size_t)row * KD)[tid] = o;
}

// Stage one 16KB half-tile (2 x global_load_lds per thread). Linear LDS dest +
// inverse-XOR-swizzled global source (rule 21), matching the swizzled ds_read.
__device__ __forceinline__ void stage_half(const unsigned short* __restrict__ XN,
                                           int gRowBase, int kt, unsigned char* opBase,
                                           int qhalf, bool isB, int wid, int lane) {
    #pragma unroll
    for (int j = 0; j < 2; ++j) {
        const int b = wid * 2 + j;                    // 1KB block index 0..15
        const int rs = isB ? ((b >> 2) * 64 + qhalf * 32 + (b & 3) * 8)
                           : (qhalf * 64 + (b & 7) * 8 + (b >> 3) * 128);
        const int row = rs + (lane >> 3);
        const int c = lane & 7;
        const int sc = c ^ (row & 7);
        const unsigned short* g = XN + (size_t)(gRowBase + row) * KD + kt * BK + sc * 8;
        __builtin_amdgcn_global_load_lds((const __attribute__((address_space(1))) void*)g,
                                         (__attribute__((address_space(3))) void*)(opBase + row * 128 + c * 16),
                                         16, 0, 0);
    }
}

// One phase: 12 ds_read_b128 | SB | stage | SB | barrier | lgkmcnt(0) |
// setprio(1) 16 MFMA setprio(0) | [vmcnt tail] | barrier.
// sched_barrier(0) pins keep ds_reads issued BEFORE the barrier so the
// barrier-wait covers their latency (theory-alpha fix).
#define SB __builtin_amdgcn_sched_barrier(0)
#define VMW  asm volatile("s_waitcnt vmcnt(4)" ::: "memory"); SB
#define VMW0 asm volatile("s_waitcnt vmcnt(0)" ::: "memory"); SB
#define PHASE(As, Bs, QM, QN, STAGE, TAILVM) do {                              \
    bf16x8 aF[2][4], bF[2][2];                                                 \
    _Pragma("unroll")                                                          \
    for (int kk = 0; kk < 2; ++kk) {                                           \
      _Pragma("unroll")                                                        \
      for (int mm = 0; mm < 4; ++mm) {                                         \
        const int row = wr * 128 + ((QM) * 4 + mm) * 16 + l15;                 \
        const int sl  = (kk * 4 + l4) ^ (row & 7);                             \
        aF[kk][mm] = *(const bf16x8*)(As + row * 128 + sl * 16);               \
      }                                                                        \
      _Pragma("unroll")                                                        \
      for (int nn = 0; nn < 2; ++nn) {                                         \
        const int row = wc * 64 + ((QN) * 2 + nn) * 16 + l15;                  \
        const int sl  = (kk * 4 + l4) ^ (row & 7);                             \
        bF[kk][nn] = *(const bf16x8*)(Bs + row * 128 + sl * 16);               \
      }                                                                        \
    }                                                                          \
    SB;                                                                        \
    STAGE;                                                                     \
    SB;                                                                        \
    __builtin_amdgcn_s_barrier();                                              \
    asm volatile("s_waitcnt lgkmcnt(0)" ::: "memory");                         \
    SB;                                                                        \
    __builtin_amdgcn_s_setprio(1);                                             \
    _Pragma("unroll")                                                          \
    for (int kk = 0; kk < 2; ++kk)                                             \
      _Pragma("unroll")                                                        \
      for (int mm = 0; mm < 4; ++mm)                                           \
        _Pragma("unroll")                                                      \
        for (int nn = 0; nn < 2; ++nn)                                         \
          acc[(QM) * 4 + mm][(QN) * 2 + nn] = __builtin_amdgcn_mfma_f32_16x16x32_bf16( \
              aF[kk][mm], bF[kk][nn], acc[(QM) * 4 + mm][(QN) * 2 + nn], 0, 0, 0);     \
    __builtin_amdgcn_s_setprio(0);                                             \
    TAILVM;                                                                    \
    __builtin_amdgcn_s_barrier();                                              \
    SB;                                                                        \
  } while (0)

// Kernel 2: 256x256-tile 8-phase double-buffered GEMM (S = XN*XN^T), upper
// triangle only, fused exp + row/col sums + pos logits.
__global__ __launch_bounds__(512, 2) void gemm_fused_kernel(const unsigned short* __restrict__ XN,
                                                            float* __restrict__ sumexp,
                                                            float* __restrict__ poslogit) {
    __shared__ __align__(16) unsigned char lds[131072];   // slot0: A,B ; slot1: A,B

    // XCD swizzle (528 % 8 == 0) then triangular decode b -> (bi <= bj).
    const int b = (blockIdx.x & 7) * (NTRI / 8) + (blockIdx.x >> 3);
    int bi = (int)(32.5f - sqrtf(32.5f * 32.5f - 2.0f * (float)b));
    while ((bi + 1) * (65 - (bi + 1)) / 2 <= b) ++bi;
    while (bi * (65 - bi) / 2 > b) --bi;
    const int bj = bi + (b - bi * (65 - bi) / 2);

    const int rowBase = bi * BM;
    const int colBase = bj * BM;
    const bool offdiag = (bi != bj);

    const int tid  = threadIdx.x;
    const int lane = tid & 63;
    const int wid  = tid >> 6;         // 0..7
    const int wr   = wid >> 2;         // 0..1  (wave row: 128 output rows each)
    const int wc   = wid & 3;          // 0..3  (wave col: 64 output cols each)
    const int l15  = lane & 15;
    const int l4   = lane >> 4;

    unsigned char* A0 = lds;
    unsigned char* B0 = lds + 32768;
    unsigned char* A1 = lds + 65536;
    unsigned char* B1 = lds + 98304;

    f32x4 acc[8][4] = {};

    // Prologue: tile0 (4 halves) -> slot0; h0 halves of tile1 -> slot1.
    stage_half(XN, colBase, 0, B0, 0, true , wid, lane);
    stage_half(XN, rowBase, 0, A0, 0, false, wid, lane);
    stage_half(XN, rowBase, 0, A0, 1, false, wid, lane);
    stage_half(XN, colBase, 0, B0, 1, true , wid, lane);
    stage_half(XN, colBase, 1, B1, 0, true , wid, lane);
    stage_half(XN, rowBase, 1, A1, 0, false, wid, lane);
    asm volatile("s_waitcnt vmcnt(4)" ::: "memory");       // tile0 landed; t1-h0 in flight
    SB;
    __builtin_amdgcn_s_barrier();

    // Full iterations i=0..2: compute tiles 2i (slot0, ph1-4) and 2i+1 (slot1,
    // ph5-8); stage t1-h1 (ph1,2), t2 all (ph3-6), t3-h0 (ph7,8).
    // vmcnt(4) at ph4/ph8 = 2 half-tiles in flight (ledger-verified; vmcnt(6)
    // would race ph2's h1 reads -- do not deepen).
    for (int i = 0; i < 3; ++i) {
        const int t1 = 2 * i + 1;
        const int t2 = 2 * i + 2;
        const int t3 = 2 * i + 3;
        PHASE(A0, B0, 0, 0, stage_half(XN, rowBase, t1, A1, 1, false, wid, lane), );
        PHASE(A0, B0, 1, 0, stage_half(XN, colBase, t1, B1, 1, true , wid, lane), );
        PHASE(A0, B0, 0, 1, stage_half(XN, colBase, t2, B0, 0, true , wid, lane), );
        PHASE(A0, B0, 1, 1, stage_half(XN, rowBase, t2, A0, 0, false, wid, lane), VMW);
        PHASE(A1, B1, 0, 0, stage_half(XN, rowBase, t2, A0, 1, false, wid, lane), );
        PHASE(A1, B1, 1, 0, stage_half(XN, colBase, t2, B0, 1, true , wid, lane), );
        PHASE(A1, B1, 0, 1, stage_half(XN, colBase, t3, B1, 0, true , wid, lane), );
        PHASE(A1, B1, 1, 1, stage_half(XN, rowBase, t3, A1, 0, false, wid, lane), VMW);
    }
    // Peeled final iteration: tiles 6 (slot0) and 7 (slot1). Only t7's h1
    // halves still need staging (ph1,2); vmcnt(0) at ph4 covers t7-h0 (staged
    // iter2 ph7/8) + t7-h1 before ph5 reads slot1. No garbage stages.
    PHASE(A0, B0, 0, 0, stage_half(XN, rowBase, 7, A1, 1, false, wid, lane), );
    PHASE(A0, B0, 1, 0, stage_half(XN, colBase, 7, B1, 1, true , wid, lane), );
    PHASE(A0, B0, 0, 1, , );
    PHASE(A0, B0, 1, 1, , VMW0);
    PHASE(A1, B1, 0, 0, , );
    PHASE(A1, B1, 1, 0, , );
    PHASE(A1, B1, 0, 1, , );
    PHASE(A1, B1, 1, 1, , );

    __syncthreads();   // protect LDS overlay below

    // Epilogue. C/D map: col = l15, row = l4*4 + reg.
    float* rowsum = (float*)lds;
    float* colsum = rowsum + BM;
    if (tid < BM) { rowsum[tid] = 0.0f; colsum[tid] = 0.0f; }
    __syncthreads();

    float cs[4] = {0.0f, 0.0f, 0.0f, 0.0f};
    #pragma unroll
    for (int m = 0; m < 8; ++m) {
        #pragma unroll
        for (int r = 0; r < 4; ++r) {
            const int row_l = wr * 128 + m * 16 + l4 * 4 + r;
            const int grow = rowBase + row_l;
            const int prow = grow < HALF_N ? grow + HALF_N : grow - HALF_N;
            float p = 0.0f;
            #pragma unroll
            for (int n = 0; n < 4; ++n) {
                const int gcol = colBase + wc * 64 + n * 16 + l15;
                const float s = acc[m][n][r] * TEMP_INV;
                const float e = (gcol != grow) ? __expf(s) : 0.0f;
                p += e;
                cs[n] += e;
                if (gcol == prow) {          // strictly upper triangle (bj = bi+16)
                    poslogit[grow] = s;
                    poslogit[gcol] = s;      // mirrored entry (pos involution)
                }
            }
            p += __shfl_xor(p, 1);
            p += __shfl_xor(p, 2);
            p += __shfl_xor(p, 4);
            p += __shfl_xor(p, 8);
            if (l15 == 0) atomicAdd(&rowsum[row_l], p);
        }
    }
    if (offdiag) {
        #pragma unroll
        for (int n = 0; n < 4; ++n) {
            float c = cs[n];
            c += __shfl_xor(c, 16);
            c += __shfl_xor(c, 32);
            if (l4 == 0) atomicAdd(&colsum[wc * 64 + n * 16 + l15], c);
        }
    }
    __syncthreads();
    if (tid < BM) {
        atomicAdd(&sumexp[rowBase + tid], rowsum[tid]);
        if (offdiag) atomicAdd(&sumexp[colBase + tid], colsum[tid]);
    }
}

// Kernel 3: loss = sum_i log(sumexp_i) - poslogit_i
__global__ __launch_bounds__(256) void finalize_kernel(const float* __restrict__ sumexp,
                                                       const float* __restrict__ poslogit,
                                                       float* __restrict__ out) {
    const int i = blockIdx.x * 256 + threadIdx.x;
    float li = logf(sumexp[i]) - poslogit[i];
    #pragma unroll
    for (int off = 32; off >= 1; off >>= 1) li += __shfl_xor(li, off);
    __shared__ float wss[4];
    if ((threadIdx.x & 63) == 0) wss[threadIdx.x >> 6] = li;
    __syncthreads();
    if (threadIdx.x == 0) atomicAdd(out, wss[0] + wss[1] + wss[2] + wss[3]);
}

extern "C" void kernel_launch(void* const* d_in, const int* in_sizes, int n_in,
                              void* d_out, int out_size, void* d_ws, size_t ws_size,
                              hipStream_t stream) {
    const float* X = (const float*)d_in[0];
    float* out = (float*)d_out;

    unsigned short* XN = (unsigned short*)d_ws;                       // 8 MB bf16
    float* sumexp   = (float*)((char*)d_ws + (size_t)NROWS * KD * 2); // 32 KB
    float* poslogit = sumexp + NROWS;                                 // 32 KB

    normalize_kernel<<<NROWS, 256, 0, stream>>>(X, XN, sumexp, out);
    gemm_fused_kernel<<<NTRI, 512, 0, stream>>>(XN, sumexp, poslogit);
    finalize_kernel<<<NROWS / 256, 256, 0, stream>>>(sumexp, poslogit, out);
}

// Round 6
// 81.454 us; speedup vs baseline: 1.1470x; 1.1372x over previous
//
#include <hip/hip_runtime.h>
#include <hip/hip_bf16.h>
#include <math.h>

#define NROWS 8192
#define HALF_N 4096
#define KD 512
#define TILE 128
#define BK32 32
#define NKT 16                    // KD / BK32
#define TEMP_INV 2.0f
#define NBLK 64                   // NROWS / TILE
#define NTRI 2080                 // NBLK*(NBLK+1)/2

typedef __attribute__((ext_vector_type(8))) short bf16x8;
typedef __attribute__((ext_vector_type(4))) float f32x4;

__device__ __forceinline__ unsigned short f2bf(float f) {
    unsigned int u = __float_as_uint(f);
    u = (u + 0x7FFFu + ((u >> 16) & 1u)) >> 16;   // round-to-nearest-even
    return (unsigned short)u;
}

// Kernel 1: row-normalize f32 -> bf16, zero accumulators.
__global__ __launch_bounds__(256) void normalize_kernel(const float* __restrict__ X,
                                                        unsigned short* __restrict__ XN,
                                                        float* __restrict__ sumexp,
                                                        float* __restrict__ out) {
    const int row = blockIdx.x;
    const int tid = threadIdx.x;
    const int gz = row * 256 + tid;
    if (gz < NROWS) sumexp[gz] = 0.0f;
    if (gz == 0) out[0] = 0.0f;

    const float2 v = reinterpret_cast<const float2*>(X + (size_t)row * KD)[tid];
    float ss = v.x * v.x + v.y * v.y;
    #pragma unroll
    for (int off = 32; off >= 1; off >>= 1) ss += __shfl_xor(ss, off);
    __shared__ float wss[4];
    if ((tid & 63) == 0) wss[tid >> 6] = ss;
    __syncthreads();
    const float tot = wss[0] + wss[1] + wss[2] + wss[3];
    const float scale = 1.0f / fmaxf(sqrtf(tot), 1e-6f);
    ushort2 o;
    o.x = f2bf(v.x * scale);
    o.y = f2bf(v.y * scale);
    reinterpret_cast<ushort2*>(XN + (size_t)row * KD)[tid] = o;
}

// Stage one K-tile (A 8KB + B 8KB) into slot t&3. Linear LDS dest (wave-uniform
// base + lane*16); linear global source (no swizzle needed: 64-B rows already
// reach the b128 bank floor on the read side).
__device__ __forceinline__ void stage_tile(const unsigned short* __restrict__ XN,
                                           unsigned char* lds, int rowBase, int colBase,
                                           int t, int tid) {
    unsigned char* slot = lds + (t & 3) * 16384;
    #pragma unroll
    for (int rnd = 0; rnd < 2; ++rnd) {
        const int c = rnd * 256 + tid;            // 16-B chunk id, 0..511
        const int row = c >> 2;
        const int cc = c & 3;
        const unsigned short* gA = XN + (size_t)(rowBase + row) * KD + t * BK32 + cc * 8;
        const unsigned short* gB = XN + (size_t)(colBase + row) * KD + t * BK32 + cc * 8;
        __builtin_amdgcn_global_load_lds((const __attribute__((address_space(1))) void*)gA,
                                         (__attribute__((address_space(3))) void*)(slot + c * 16), 16, 0, 0);
        __builtin_amdgcn_global_load_lds((const __attribute__((address_space(1))) void*)gB,
                                         (__attribute__((address_space(3))) void*)(slot + 8192 + c * 16), 16, 0, 0);
    }
}

#define SB __builtin_amdgcn_sched_barrier(0)
#define VMW4 asm volatile("s_waitcnt vmcnt(4)" ::: "memory"); SB
#define VMW0 asm volatile("s_waitcnt vmcnt(0)" ::: "memory"); SB
// Phase t: 8 ds_read_b128 from slot t&3 | stage tile t+2 | barrier | lgkm(0) |
// setprio(1) 16 MFMA setprio(0) | TAIL vmcnt | barrier.
// vmcnt(4) before the end barrier == "tile t+1 landed for every wave" (each
// wave waits its own 4 oldest loads; the barrier makes it collective).
#define PH(T, STAGE, TAILVM) do {                                              \
    unsigned char* As = lds + ((T) & 3) * 16384;                               \
    unsigned char* Bs = As + 8192;                                             \
    bf16x8 aF[4], bF[4];                                                       \
    _Pragma("unroll")                                                          \
    for (int m = 0; m < 4; ++m)                                                \
        aF[m] = *(const bf16x8*)(As + (wr * 64 + m * 16 + l15) * 64 + l4 * 16);\
    _Pragma("unroll")                                                          \
    for (int n = 0; n < 4; ++n)                                                \
        bF[n] = *(const bf16x8*)(Bs + (wc * 64 + n * 16 + l15) * 64 + l4 * 16);\
    SB;                                                                        \
    STAGE;                                                                     \
    SB;                                                                        \
    __builtin_amdgcn_s_barrier();                                              \
    asm volatile("s_waitcnt lgkmcnt(0)" ::: "memory");                         \
    SB;                                                                        \
    __builtin_amdgcn_s_setprio(1);                                             \
    _Pragma("unroll")                                                          \
    for (int m = 0; m < 4; ++m)                                                \
        _Pragma("unroll")                                                      \
        for (int n = 0; n < 4; ++n)                                            \
            acc[m][n] = __builtin_amdgcn_mfma_f32_16x16x32_bf16(aF[m], bF[n], acc[m][n], 0, 0, 0); \
    __builtin_amdgcn_s_setprio(0);                                             \
    TAILVM;                                                                    \
    __builtin_amdgcn_s_barrier();                                              \
    SB;                                                                        \
  } while (0)

// Kernel 2: 128x128-tile GEMM (S = XN*XN^T), BK=32, 4-slot LDS pipeline with
// counted vmcnt(4) (2-tile lookahead), 2 blocks/CU; upper triangle only; fused
// exp + row/col sums + pos logits.
__global__ __launch_bounds__(256, 2) void gemm_fused_kernel(const unsigned short* __restrict__ XN,
                                                            float* __restrict__ sumexp,
                                                            float* __restrict__ poslogit) {
    __shared__ __align__(16) unsigned char lds[65536];   // 4 slots x (A 8K + B 8K)

    // XCD swizzle (2080 % 8 == 0) then triangular decode b -> (bi <= bj).
    const int b = (blockIdx.x & 7) * (NTRI / 8) + (blockIdx.x >> 3);
    int bi = (int)(64.5f - sqrtf(64.5f * 64.5f - 2.0f * (float)b));
    while ((bi + 1) * (129 - (bi + 1)) / 2 <= b) ++bi;
    while (bi * (129 - bi) / 2 > b) --bi;
    const int bj = bi + (b - bi * (129 - bi) / 2);

    const int rowBase = bi * TILE;
    const int colBase = bj * TILE;
    const bool offdiag = (bi != bj);

    const int tid  = threadIdx.x;
    const int lane = tid & 63;
    const int wid  = tid >> 6;          // 0..3
    const int wr   = wid >> 1;          // 0/1
    const int wc   = wid & 1;           // 0/1
    const int l15  = lane & 15;
    const int l4   = lane >> 4;

    f32x4 acc[4][4] = {};

    // Prologue: tiles 0,1 staged; wait own-4-oldest (t0) + barrier => t0 ready.
    stage_tile(XN, lds, rowBase, colBase, 0, tid);
    stage_tile(XN, lds, rowBase, colBase, 1, tid);
    VMW4;
    __builtin_amdgcn_s_barrier();

    // Main loop t=0..13: uniform counted-vmcnt phases (4 loads always in flight).
    #pragma unroll
    for (int t = 0; t < NKT - 2; ++t)
        PH(t, stage_tile(XN, lds, rowBase, colBase, t + 2, tid), VMW4);
    // Tail: t=14 (wait t15's loads), t=15 (nothing outstanding).
    PH(NKT - 2, , VMW0);
    PH(NKT - 1, , );

    __syncthreads();   // protect LDS overlay

    // Epilogue. C/D map: col = l15, row = l4*4 + reg.
    float* rowsum = (float*)lds;
    float* colsum = rowsum + TILE;
    if (tid < TILE) { rowsum[tid] = 0.0f; colsum[tid] = 0.0f; }
    __syncthreads();

    float cs[4] = {0.0f, 0.0f, 0.0f, 0.0f};   // per-n column partials (col = l15 fixed)
    #pragma unroll
    for (int m = 0; m < 4; ++m) {
        #pragma unroll
        for (int r = 0; r < 4; ++r) {
            const int row_l = wr * 64 + m * 16 + l4 * 4 + r;
            const int grow = rowBase + row_l;
            const int prow = grow < HALF_N ? grow + HALF_N : grow - HALF_N;
            float p = 0.0f;
            #pragma unroll
            for (int n = 0; n < 4; ++n) {
                const int gcol = colBase + wc * 64 + n * 16 + l15;
                const float s = acc[m][n][r] * TEMP_INV;
                const float e = (gcol != grow) ? __expf(s) : 0.0f;
                p += e;
                cs[n] += e;
                if (gcol == prow) {            // strictly upper triangle (bj = bi+32)
                    poslogit[grow] = s;
                    poslogit[gcol] = s;        // mirrored entry (pos involution)
                }
            }
            p += __shfl_xor(p, 1);
            p += __shfl_xor(p, 2);
            p += __shfl_xor(p, 4);
            p += __shfl_xor(p, 8);
            if (l15 == 0) atomicAdd(&rowsum[row_l], p);
        }
    }
    if (offdiag) {
        #pragma unroll
        for (int n = 0; n < 4; ++n) {
            float c = cs[n];
            c += __shfl_xor(c, 16);
            c += __shfl_xor(c, 32);
            if (l4 == 0) atomicAdd(&colsum[wc * 64 + n * 16 + l15], c);
        }
    }
    __syncthreads();
    if (tid < TILE) {
        atomicAdd(&sumexp[rowBase + tid], rowsum[tid]);
        if (offdiag) atomicAdd(&sumexp[colBase + tid], colsum[tid]);
    }
}

// Kernel 3: loss = sum_i log(sumexp_i) - poslogit_i
__global__ __launch_bounds__(256) void finalize_kernel(const float* __restrict__ sumexp,
                                                       const float* __restrict__ poslogit,
                                                       float* __restrict__ out) {
    const int i = blockIdx.x * 256 + threadIdx.x;
    float li = logf(sumexp[i]) - poslogit[i];
    #pragma unroll
    for (int off = 32; off >= 1; off >>= 1) li += __shfl_xor(li, off);
    __shared__ float wss[4];
    if ((threadIdx.x & 63) == 0) wss[threadIdx.x >> 6] = li;
    __syncthreads();
    if (threadIdx.x == 0) atomicAdd(out, wss[0] + wss[1] + wss[2] + wss[3]);
}

extern "C" void kernel_launch(void* const* d_in, const int* in_sizes, int n_in,
                              void* d_out, int out_size, void* d_ws, size_t ws_size,
                              hipStream_t stream) {
    const float* X = (const float*)d_in[0];
    float* out = (float*)d_out;

    unsigned short* XN = (unsigned short*)d_ws;                       // 8 MB bf16
    float* sumexp   = (float*)((char*)d_ws + (size_t)NROWS * KD * 2); // 32 KB
    float* poslogit = sumexp + NROWS;                                 // 32 KB

    normalize_kernel<<<NROWS, 256, 0, stream>>>(X, XN, sumexp, out);
    gemm_fused_kernel<<<NTRI, 256, 0, stream>>>(XN, sumexp, poslogit);
    finalize_kernel<<<NROWS / 256, 256, 0, stream>>>(sumexp, poslogit, out);
}

// Round 7
// 66.691 us; speedup vs baseline: 1.4009x; 1.2214x over previous
//
#include <hip/hip_runtime.h>
#include <hip/hip_bf16.h>
#include <math.h>

#define NROWS 8192
#define HALF_N 4096
#define KD 512
#define TILE 128
#define BK32 32
#define NKT 16                    // KD / BK32
#define TEMP_INV 2.0f
#define NBLK 64                   // NROWS / TILE
#define NTRI 2080                 // NBLK*(NBLK+1)/2

typedef __attribute__((ext_vector_type(8))) short bf16x8;
typedef __attribute__((ext_vector_type(4))) float f32x4;

__device__ __forceinline__ unsigned short f2bf(float f) {
    unsigned int u = __float_as_uint(f);
    u = (u + 0x7FFFu + ((u >> 16) & 1u)) >> 16;   // round-to-nearest-even
    return (unsigned short)u;
}

// Kernel 1: row-normalize f32 -> bf16, zero accumulators.
__global__ __launch_bounds__(256) void normalize_kernel(const float* __restrict__ X,
                                                        unsigned short* __restrict__ XN,
                                                        float* __restrict__ sumexp,
                                                        float* __restrict__ out) {
    const int row = blockIdx.x;
    const int tid = threadIdx.x;
    const int gz = row * 256 + tid;
    if (gz < NROWS) sumexp[gz] = 0.0f;
    if (gz == 0) out[0] = 0.0f;

    const float2 v = reinterpret_cast<const float2*>(X + (size_t)row * KD)[tid];
    float ss = v.x * v.x + v.y * v.y;
    #pragma unroll
    for (int off = 32; off >= 1; off >>= 1) ss += __shfl_xor(ss, off);
    __shared__ float wss[4];
    if ((tid & 63) == 0) wss[tid >> 6] = ss;
    __syncthreads();
    const float tot = wss[0] + wss[1] + wss[2] + wss[3];
    const float scale = 1.0f / fmaxf(sqrtf(tot), 1e-6f);
    ushort2 o;
    o.x = f2bf(v.x * scale);
    o.y = f2bf(v.y * scale);
    reinterpret_cast<ushort2*>(XN + (size_t)row * KD)[tid] = o;
}

// Stage one K-tile (A 8KB + B 8KB) into slot t%3. Linear LDS dest (gload_lds
// requirement); global source column is XOR-permuted by row (rule 21) to match
// the bank-spreading swizzle on the ds_read side.
__device__ __forceinline__ void stage_tile(const unsigned short* __restrict__ XN,
                                           unsigned char* lds, int rowBase, int colBase,
                                           int t, int tid) {
    unsigned char* slot = lds + (t % 3) * 16384;
    #pragma unroll
    for (int rnd = 0; rnd < 2; ++rnd) {
        const int c = rnd * 256 + tid;            // 16-B chunk id, 0..511
        const int row = c >> 2;
        const int scc = (c & 3) ^ ((row >> 1) & 3);   // inverse swizzle (involution)
        const unsigned short* gA = XN + (size_t)(rowBase + row) * KD + t * BK32 + scc * 8;
        const unsigned short* gB = XN + (size_t)(colBase + row) * KD + t * BK32 + scc * 8;
        __builtin_amdgcn_global_load_lds((const __attribute__((address_space(1))) void*)gA,
                                         (__attribute__((address_space(3))) void*)(slot + c * 16), 16, 0, 0);
        __builtin_amdgcn_global_load_lds((const __attribute__((address_space(1))) void*)gB,
                                         (__attribute__((address_space(3))) void*)(slot + 8192 + c * 16), 16, 0, 0);
    }
}

#define SB __builtin_amdgcn_sched_barrier(0)
#define VMW4 asm volatile("s_waitcnt vmcnt(4)" ::: "memory"); SB
#define VMW0 asm volatile("s_waitcnt vmcnt(0)" ::: "memory"); SB
// Phase t: 8 swizzled ds_read_b128 from slot t%3 | stage tile t+2 -> slot
// (t+2)%3 | barrier | lgkm(0) | setprio(1) 16 MFMA setprio(0) | TAIL | barrier.
// Bank math: start bank = (l15&1)*16 + (l4 ^ ((l15>>1)&3))*4 -> 2 lanes per
// 4-bank group = ds_read_b128 floor (conflict-free).
#define PH(T, STAGE, TAILVM) do {                                              \
    unsigned char* As = lds + ((T) % 3) * 16384;                               \
    unsigned char* Bs = As + 8192;                                             \
    bf16x8 aF[4], bF[4];                                                       \
    _Pragma("unroll")                                                          \
    for (int m = 0; m < 4; ++m) {                                              \
        const int row = wr * 64 + m * 16 + l15;                                \
        aF[m] = *(const bf16x8*)(As + row * 64 + (l4 ^ ((row >> 1) & 3)) * 16);\
    }                                                                          \
    _Pragma("unroll")                                                          \
    for (int n = 0; n < 4; ++n) {                                              \
        const int row = wc * 64 + n * 16 + l15;                                \
        bF[n] = *(const bf16x8*)(Bs + row * 64 + (l4 ^ ((row >> 1) & 3)) * 16);\
    }                                                                          \
    SB;                                                                        \
    STAGE;                                                                     \
    SB;                                                                        \
    __builtin_amdgcn_s_barrier();                                              \
    asm volatile("s_waitcnt lgkmcnt(0)" ::: "memory");                         \
    SB;                                                                        \
    __builtin_amdgcn_s_setprio(1);                                             \
    _Pragma("unroll")                                                          \
    for (int m = 0; m < 4; ++m)                                                \
        _Pragma("unroll")                                                      \
        for (int n = 0; n < 4; ++n)                                            \
            acc[m][n] = __builtin_amdgcn_mfma_f32_16x16x32_bf16(aF[m], bF[n], acc[m][n], 0, 0, 0); \
    __builtin_amdgcn_s_setprio(0);                                             \
    TAILVM;                                                                    \
    __builtin_amdgcn_s_barrier();                                              \
    SB;                                                                        \
  } while (0)

// Supertile-aware triangular decode: 4x4 grid of 16x16-block supertiles.
// Order: (0,0)(0,1)(0,2)(0,3)(1,1)(1,2)(1,3)(2,2)(2,3)(3,3); diag STs have
// 136 blocks, off-diag 256. Working set per ST = 32 panels = 4MB = one L2.
__device__ __forceinline__ void decode_tri(int b, int& bi, int& bj) {
    const int pref[10] = {136, 392, 648, 904, 1040, 1296, 1552, 1688, 1944, 2080};
    const int sij[10]  = {0x00, 0x01, 0x02, 0x03, 0x11, 0x12, 0x13, 0x22, 0x23, 0x33};
    int st = 0;
    #pragma unroll
    for (int k = 0; k < 9; ++k) st += (b >= pref[k]);
    const int base = st ? pref[st - 1] : 0;
    const int L = b - base;
    const int si = sij[st] >> 4, sj = sij[st] & 15;
    int li, lj;
    if (si == sj) {            // local 16-row triangle: row li offset = li*(33-li)/2
        li = (int)(16.5f - sqrtf(16.5f * 16.5f - 2.0f * (float)L));
        while ((li + 1) * (33 - (li + 1)) / 2 <= L) ++li;
        while (li * (33 - li) / 2 > L) --li;
        lj = li + (L - li * (33 - li) / 2);
    } else {                   // 16x16 full, snake order for panel adjacency
        li = L >> 4;
        lj = L & 15;
        if (li & 1) lj = 15 - lj;
    }
    bi = si * 16 + li;
    bj = sj * 16 + lj;
}

// Kernel 2: 128x128-tile GEMM (S = XN*XN^T), BK=32, 3-slot LDS pipeline
// (48KB -> 3 blocks/CU) with counted vmcnt(4); upper triangle via supertiled
// decode; fused exp + row/col sums + pos logits.
__global__ __launch_bounds__(256, 3) void gemm_fused_kernel(const unsigned short* __restrict__ XN,
                                                            float* __restrict__ sumexp,
                                                            float* __restrict__ poslogit) {
    __shared__ __align__(16) unsigned char lds[49152];   // 3 slots x (A 8K + B 8K)

    // XCD chunking: 260 consecutive supertile-ordered indices per XCD.
    const int b = (blockIdx.x & 7) * (NTRI / 8) + (blockIdx.x >> 3);
    int bi, bj;
    decode_tri(b, bi, bj);

    const int rowBase = bi * TILE;
    const int colBase = bj * TILE;
    const bool offdiag = (bi != bj);

    const int tid  = threadIdx.x;
    const int lane = tid & 63;
    const int wid  = tid >> 6;          // 0..3
    const int wr   = wid >> 1;          // 0/1
    const int wc   = wid & 1;           // 0/1
    const int l15  = lane & 15;
    const int l4   = lane >> 4;

    f32x4 acc[4][4] = {};

    // Prologue: tiles 0,1 staged; wait own-4-oldest (t0) + barrier => t0 ready.
    stage_tile(XN, lds, rowBase, colBase, 0, tid);
    stage_tile(XN, lds, rowBase, colBase, 1, tid);
    VMW4;
    __builtin_amdgcn_s_barrier();

    // Main loop t=0..13: uniform counted-vmcnt phases (4 loads always in flight).
    #pragma unroll
    for (int t = 0; t < NKT - 2; ++t)
        PH(t, stage_tile(XN, lds, rowBase, colBase, t + 2, tid), VMW4);
    // Tail: t=14 (wait t15's loads), t=15 (nothing outstanding).
    PH(NKT - 2, , VMW0);
    PH(NKT - 1, , );

    __syncthreads();   // protect LDS overlay

    // Epilogue. C/D map: col = l15, row = l4*4 + reg.
    float* rowsum = (float*)lds;
    float* colsum = rowsum + TILE;
    if (tid < TILE) { rowsum[tid] = 0.0f; colsum[tid] = 0.0f; }
    __syncthreads();

    float cs[4] = {0.0f, 0.0f, 0.0f, 0.0f};   // per-n column partials (col = l15 fixed)
    #pragma unroll
    for (int m = 0; m < 4; ++m) {
        #pragma unroll
        for (int r = 0; r < 4; ++r) {
            const int row_l = wr * 64 + m * 16 + l4 * 4 + r;
            const int grow = rowBase + row_l;
            const int prow = grow < HALF_N ? grow + HALF_N : grow - HALF_N;
            float p = 0.0f;
            #pragma unroll
            for (int n = 0; n < 4; ++n) {
                const int gcol = colBase + wc * 64 + n * 16 + l15;
                const float s = acc[m][n][r] * TEMP_INV;
                const float e = (gcol != grow) ? __expf(s) : 0.0f;
                p += e;
                cs[n] += e;
                if (gcol == prow) {            // strictly upper triangle
                    poslogit[grow] = s;
                    poslogit[gcol] = s;        // mirrored entry (pos involution)
                }
            }
            p += __shfl_xor(p, 1);
            p += __shfl_xor(p, 2);
            p += __shfl_xor(p, 4);
            p += __shfl_xor(p, 8);
            if (l15 == 0) atomicAdd(&rowsum[row_l], p);
        }
    }
    if (offdiag) {
        #pragma unroll
        for (int n = 0; n < 4; ++n) {
            float c = cs[n];
            c += __shfl_xor(c, 16);
            c += __shfl_xor(c, 32);
            if (l4 == 0) atomicAdd(&colsum[wc * 64 + n * 16 + l15], c);
        }
    }
    __syncthreads();
    if (tid < TILE) {
        atomicAdd(&sumexp[rowBase + tid], rowsum[tid]);
        if (offdiag) atomicAdd(&sumexp[colBase + tid], colsum[tid]);
    }
}

// Kernel 3: loss = sum_i log(sumexp_i) - poslogit_i
__global__ __launch_bounds__(256) void finalize_kernel(const float* __restrict__ sumexp,
                                                       const float* __restrict__ poslogit,
                                                       float* __restrict__ out) {
    const int i = blockIdx.x * 256 + threadIdx.x;
    float li = logf(sumexp[i]) - poslogit[i];
    #pragma unroll
    for (int off = 32; off >= 1; off >>= 1) li += __shfl_xor(li, off);
    __shared__ float wss[4];
    if ((threadIdx.x & 63) == 0) wss[threadIdx.x >> 6] = li;
    __syncthreads();
    if (threadIdx.x == 0) atomicAdd(out, wss[0] + wss[1] + wss[2] + wss[3]);
}

extern "C" void kernel_launch(void* const* d_in, const int* in_sizes, int n_in,
                              void* d_out, int out_size, void* d_ws, size_t ws_size,
                              hipStream_t stream) {
    const float* X = (const float*)d_in[0];
    float* out = (float*)d_out;

    unsigned short* XN = (unsigned short*)d_ws;                       // 8 MB bf16
    float* sumexp   = (float*)((char*)d_ws + (size_t)NROWS * KD * 2); // 32 KB
    float* poslogit = sumexp + NROWS;                                 // 32 KB

    normalize_kernel<<<NROWS, 256, 0, stream>>>(X, XN, sumexp, out);
    gemm_fused_kernel<<<NTRI, 256, 0, stream>>>(XN, sumexp, poslogit);
    finalize_kernel<<<NROWS / 256, 256, 0, stream>>>(sumexp, poslogit, out);
}

// Round 8
// 58.648 us; speedup vs baseline: 1.5930x; 1.1371x over previous
//
#include <hip/hip_runtime.h>
#include <hip/hip_bf16.h>
#include <hip/hip_fp8.h>
#include <math.h>

#define NROWS 8192
#define HALF_N 4096
#define KD 512
#define TILE 128
#define BK 64                     // fp8: 64 elements = 64 B per row-tile
#define NKT 8                     // KD / BK
#define TEMP_INV 2.0f
#define NBLK 64                   // NROWS / TILE
#define NTRI 2080                 // NBLK*(NBLK+1)/2

typedef __attribute__((ext_vector_type(4))) float f32x4;

// Kernel 1: row-normalize f32 -> fp8 e4m3 (OCP), zero accumulators.
__global__ __launch_bounds__(256) void normalize_kernel(const float* __restrict__ X,
                                                        unsigned char* __restrict__ XN8,
                                                        float* __restrict__ sumexp,
                                                        float* __restrict__ out) {
    const int row = blockIdx.x;
    const int tid = threadIdx.x;
    const int gz = row * 256 + tid;
    if (gz < NROWS) sumexp[gz] = 0.0f;
    if (gz == 0) out[0] = 0.0f;

    const float2 v = reinterpret_cast<const float2*>(X + (size_t)row * KD)[tid];
    float ss = v.x * v.x + v.y * v.y;
    #pragma unroll
    for (int off = 32; off >= 1; off >>= 1) ss += __shfl_xor(ss, off);
    __shared__ float wss[4];
    if ((tid & 63) == 0) wss[tid >> 6] = ss;
    __syncthreads();
    const float tot = wss[0] + wss[1] + wss[2] + wss[3];
    const float scale = 1.0f / fmaxf(sqrtf(tot), 1e-6f);
    __hip_fp8_e4m3 qx(v.x * scale);
    __hip_fp8_e4m3 qy(v.y * scale);
    uchar2 o;
    o.x = qx.__x;
    o.y = qy.__x;
    reinterpret_cast<uchar2*>(XN8 + (size_t)row * KD)[tid] = o;
}

// Stage one K-tile (A 8KB + B 8KB, fp8) into slot t%3. Linear LDS dest;
// global source 16B-chunk is XOR-permuted by row (rule 21: involution applied
// on source AND read side), matching the bank swizzle below.
__device__ __forceinline__ void stage_tile(const unsigned char* __restrict__ XN8,
                                           unsigned char* lds, int rowBase, int colBase,
                                           int t, int tid) {
    unsigned char* slot = lds + (t % 3) * 16384;
    #pragma unroll
    for (int rnd = 0; rnd < 2; ++rnd) {
        const int c = rnd * 256 + tid;            // 16-B chunk id, 0..511
        const int row = c >> 2;
        const int scc = (c & 3) ^ ((row >> 1) & 3);   // inverse swizzle (involution)
        const unsigned char* gA = XN8 + (size_t)(rowBase + row) * KD + t * BK + scc * 16;
        const unsigned char* gB = XN8 + (size_t)(colBase + row) * KD + t * BK + scc * 16;
        __builtin_amdgcn_global_load_lds((const __attribute__((address_space(1))) void*)gA,
                                         (__attribute__((address_space(3))) void*)(slot + c * 16), 16, 0, 0);
        __builtin_amdgcn_global_load_lds((const __attribute__((address_space(1))) void*)gB,
                                         (__attribute__((address_space(3))) void*)(slot + 8192 + c * 16), 16, 0, 0);
    }
}

#define SB __builtin_amdgcn_sched_barrier(0)
#define VMW4 asm volatile("s_waitcnt vmcnt(4)" ::: "memory"); SB
#define VMW0 asm volatile("s_waitcnt vmcnt(0)" ::: "memory"); SB
// Phase t (BK=64): 16 swizzled ds_read_b64 from slot t%3 | stage tile t+2 |
// barrier | lgkm(0) | setprio(1) 32 fp8-MFMA setprio(0) | TAIL vmcnt | barrier.
// Frag (row, kk, l4) needs k-bytes [kk*32+l4*8, +8): chunk c = kk*2+(l4>>1),
// swizzled c' = c ^ ((row>>1)&3), sub-offset (l4&1)*8. Bank check: every bank
// touched exactly 4x per b64 instr (the wave64 minimum) -- conflict-free.
#define PH(T, STAGE, TAILVM) do {                                              \
    unsigned char* As = lds + ((T) % 3) * 16384;                               \
    unsigned char* Bs = As + 8192;                                             \
    long aF[2][4], bF[2][4];                                                   \
    _Pragma("unroll")                                                          \
    for (int kk = 0; kk < 2; ++kk) {                                           \
      _Pragma("unroll")                                                        \
      for (int m = 0; m < 4; ++m) {                                            \
        const int row = wr * 64 + m * 16 + l15;                                \
        const int cp = (kk * 2 + (l4 >> 1)) ^ ((row >> 1) & 3);                \
        aF[kk][m] = *(const long*)(As + row * 64 + cp * 16 + (l4 & 1) * 8);    \
      }                                                                        \
      _Pragma("unroll")                                                        \
      for (int n = 0; n < 4; ++n) {                                            \
        const int row = wc * 64 + n * 16 + l15;                                \
        const int cp = (kk * 2 + (l4 >> 1)) ^ ((row >> 1) & 3);                \
        bF[kk][n] = *(const long*)(Bs + row * 64 + cp * 16 + (l4 & 1) * 8);    \
      }                                                                        \
    }                                                                          \
    SB;                                                                        \
    STAGE;                                                                     \
    SB;                                                                        \
    __builtin_amdgcn_s_barrier();                                              \
    asm volatile("s_waitcnt lgkmcnt(0)" ::: "memory");                         \
    SB;                                                                        \
    __builtin_amdgcn_s_setprio(1);                                             \
    _Pragma("unroll")                                                          \
    for (int kk = 0; kk < 2; ++kk)                                             \
        _Pragma("unroll")                                                      \
        for (int m = 0; m < 4; ++m)                                            \
            _Pragma("unroll")                                                  \
            for (int n = 0; n < 4; ++n)                                        \
                acc[m][n] = __builtin_amdgcn_mfma_f32_16x16x32_fp8_fp8(        \
                    aF[kk][m], bF[kk][n], acc[m][n], 0, 0, 0);                 \
    __builtin_amdgcn_s_setprio(0);                                             \
    TAILVM;                                                                    \
    __builtin_amdgcn_s_barrier();                                              \
    SB;                                                                        \
  } while (0)

// Supertile-aware triangular decode: 4x4 grid of 16x16-block supertiles.
__device__ __forceinline__ void decode_tri(int b, int& bi, int& bj) {
    const int pref[10] = {136, 392, 648, 904, 1040, 1296, 1552, 1688, 1944, 2080};
    const int sij[10]  = {0x00, 0x01, 0x02, 0x03, 0x11, 0x12, 0x13, 0x22, 0x23, 0x33};
    int st = 0;
    #pragma unroll
    for (int k = 0; k < 9; ++k) st += (b >= pref[k]);
    const int base = st ? pref[st - 1] : 0;
    const int L = b - base;
    const int si = sij[st] >> 4, sj = sij[st] & 15;
    int li, lj;
    if (si == sj) {
        li = (int)(16.5f - sqrtf(16.5f * 16.5f - 2.0f * (float)L));
        while ((li + 1) * (33 - (li + 1)) / 2 <= L) ++li;
        while (li * (33 - li) / 2 > L) --li;
        lj = li + (L - li * (33 - li) / 2);
    } else {
        li = L >> 4;
        lj = L & 15;
        if (li & 1) lj = 15 - lj;
    }
    bi = si * 16 + li;
    bj = sj * 16 + lj;
}

// Kernel 2: fp8 128x128-tile GEMM (S = XN*XN^T), BK=64, 3-slot LDS pipeline
// with counted vmcnt(4); supertiled upper triangle; fused exp + row/col sums +
// pos logits.
__global__ __launch_bounds__(256, 3) void gemm_fused_kernel(const unsigned char* __restrict__ XN8,
                                                            float* __restrict__ sumexp,
                                                            float* __restrict__ poslogit) {
    __shared__ __align__(16) unsigned char lds[49152];   // 3 slots x (A 8K + B 8K)

    const int b = (blockIdx.x & 7) * (NTRI / 8) + (blockIdx.x >> 3);
    int bi, bj;
    decode_tri(b, bi, bj);

    const int rowBase = bi * TILE;
    const int colBase = bj * TILE;
    const bool offdiag = (bi != bj);

    const int tid  = threadIdx.x;
    const int lane = tid & 63;
    const int wid  = tid >> 6;          // 0..3
    const int wr   = wid >> 1;          // 0/1
    const int wc   = wid & 1;           // 0/1
    const int l15  = lane & 15;
    const int l4   = lane >> 4;

    f32x4 acc[4][4] = {};

    // Prologue: tiles 0,1 staged (4 loads/thread each); vmcnt(4)+barrier => t0 ready.
    stage_tile(XN8, lds, rowBase, colBase, 0, tid);
    stage_tile(XN8, lds, rowBase, colBase, 1, tid);
    VMW4;
    __builtin_amdgcn_s_barrier();

    // Main loop t=0..5: uniform counted-vmcnt phases (4 loads always in flight).
    #pragma unroll
    for (int t = 0; t < NKT - 2; ++t)
        PH(t, stage_tile(XN8, lds, rowBase, colBase, t + 2, tid), VMW4);
    // Tail: t=6 (drain t7's loads), t=7 (nothing outstanding).
    PH(NKT - 2, , VMW0);
    PH(NKT - 1, , );

    __syncthreads();   // protect LDS overlay

    // Epilogue. C/D map: col = l15, row = l4*4 + reg (shape-determined,
    // dtype-independent; S symmetric -> transpose-safe).
    float* rowsum = (float*)lds;
    float* colsum = rowsum + TILE;
    if (tid < TILE) { rowsum[tid] = 0.0f; colsum[tid] = 0.0f; }
    __syncthreads();

    float cs[4] = {0.0f, 0.0f, 0.0f, 0.0f};
    #pragma unroll
    for (int m = 0; m < 4; ++m) {
        #pragma unroll
        for (int r = 0; r < 4; ++r) {
            const int row_l = wr * 64 + m * 16 + l4 * 4 + r;
            const int grow = rowBase + row_l;
            const int prow = grow < HALF_N ? grow + HALF_N : grow - HALF_N;
            float p = 0.0f;
            #pragma unroll
            for (int n = 0; n < 4; ++n) {
                const int gcol = colBase + wc * 64 + n * 16 + l15;
                const float s = acc[m][n][r] * TEMP_INV;
                const float e = (gcol != grow) ? __expf(s) : 0.0f;
                p += e;
                cs[n] += e;
                if (gcol == prow) {            // strictly upper triangle
                    poslogit[grow] = s;
                    poslogit[gcol] = s;        // mirrored entry (pos involution)
                }
            }
            p += __shfl_xor(p, 1);
            p += __shfl_xor(p, 2);
            p += __shfl_xor(p, 4);
            p += __shfl_xor(p, 8);
            if (l15 == 0) atomicAdd(&rowsum[row_l], p);
        }
    }
    if (offdiag) {
        #pragma unroll
        for (int n = 0; n < 4; ++n) {
            float c = cs[n];
            c += __shfl_xor(c, 16);
            c += __shfl_xor(c, 32);
            if (l4 == 0) atomicAdd(&colsum[wc * 64 + n * 16 + l15], c);
        }
    }
    __syncthreads();
    if (tid < TILE) {
        atomicAdd(&sumexp[rowBase + tid], rowsum[tid]);
        if (offdiag) atomicAdd(&sumexp[colBase + tid], colsum[tid]);
    }
}

// Kernel 3: loss = sum_i log(sumexp_i) - poslogit_i
__global__ __launch_bounds__(256) void finalize_kernel(const float* __restrict__ sumexp,
                                                       const float* __restrict__ poslogit,
                                                       float* __restrict__ out) {
    const int i = blockIdx.x * 256 + threadIdx.x;
    float li = logf(sumexp[i]) - poslogit[i];
    #pragma unroll
    for (int off = 32; off >= 1; off >>= 1) li += __shfl_xor(li, off);
    __shared__ float wss[4];
    if ((threadIdx.x & 63) == 0) wss[threadIdx.x >> 6] = li;
    __syncthreads();
    if (threadIdx.x == 0) atomicAdd(out, wss[0] + wss[1] + wss[2] + wss[3]);
}

extern "C" void kernel_launch(void* const* d_in, const int* in_sizes, int n_in,
                              void* d_out, int out_size, void* d_ws, size_t ws_size,
                              hipStream_t stream) {
    const float* X = (const float*)d_in[0];
    float* out = (float*)d_out;

    unsigned char* XN8 = (unsigned char*)d_ws;                        // 4 MB fp8
    float* sumexp   = (float*)((char*)d_ws + (size_t)NROWS * KD);     // 32 KB
    float* poslogit = sumexp + NROWS;                                 // 32 KB

    normalize_kernel<<<NROWS, 256, 0, stream>>>(X, XN8, sumexp, out);
    gemm_fused_kernel<<<NTRI, 256, 0, stream>>>(XN8, sumexp, poslogit);
    finalize_kernel<<<NROWS / 256, 256, 0, stream>>>(sumexp, poslogit, out);
}

// Round 9
// 57.514 us; speedup vs baseline: 1.6245x; 1.0197x over previous
//
#include <hip/hip_runtime.h>
#include <hip/hip_bf16.h>
#include <hip/hip_fp8.h>
#include <math.h>

#define NROWS 8192
#define HALF_N 4096
#define KD 512
#define TILE 128
#define BK 64                     // fp8: 64 B per row per K-tile
#define NKT 8                     // KD / BK
#define TEMP_INV 2.0f
#define NBLK 64                   // NROWS / TILE
#define NTRI 2080                 // NBLK*(NBLK+1)/2

typedef __attribute__((ext_vector_type(4))) float f32x4;
typedef __attribute__((ext_vector_type(2))) long lx2;   // 16-B LDS read

// Kernel 1: row-normalize f32 -> fp8 e4m3, written in k-PAIRED order: within
// each 64-B k-group, byte (s*32 + l4*8 + b) is stored at (l4*16 + s*8 + b),
// so one ds_read_b128 per lane yields both kk=0/kk=1 MFMA fragments.
// (Same permutation for A and B operands => dot products invariant.)
__global__ __launch_bounds__(256) void normalize_kernel(const float* __restrict__ X,
                                                        unsigned char* __restrict__ XN8,
                                                        float* __restrict__ sumexp,
                                                        float* __restrict__ out) {
    const int row = blockIdx.x;
    const int tid = threadIdx.x;
    const int gz = row * 256 + tid;
    if (gz < NROWS) sumexp[gz] = 0.0f;
    if (gz == 0) out[0] = 0.0f;

    const float2 v = reinterpret_cast<const float2*>(X + (size_t)row * KD)[tid];
    float ss = v.x * v.x + v.y * v.y;
    #pragma unroll
    for (int off = 32; off >= 1; off >>= 1) ss += __shfl_xor(ss, off);
    __shared__ float wss[4];
    if ((tid & 63) == 0) wss[tid >> 6] = ss;
    __syncthreads();
    const float tot = wss[0] + wss[1] + wss[2] + wss[3];
    const float scale = 1.0f / fmaxf(sqrtf(tot), 1e-6f);
    __hip_fp8_e4m3 qx(v.x * scale);
    __hip_fp8_e4m3 qy(v.y * scale);
    uchar2 o;
    o.x = qx.__x;
    o.y = qy.__x;
    const int k  = 2 * tid;                 // source byte index in row
    const int g  = k >> 6;                  // 64-B k-group
    const int k6 = k & 63;                  // s*32 + l4*8 + b
    const int p  = ((k6 >> 3) & 3) * 16 + (k6 >> 5) * 8 + (k6 & 7);
    *reinterpret_cast<uchar2*>(XN8 + (size_t)row * KD + g * 64 + p) = o;
}

// Stage one K-tile (A 8KB + B 8KB, fp8) into slot t%3. 512 threads: one A
// chunk + one B chunk each (2 gload_lds/thread => vmcnt steps of 2).
// Linear LDS dest; global source 16B-chunk XOR-permuted by row (rule 21),
// matching the read-side bank swizzle.
__device__ __forceinline__ void stage_tile(const unsigned char* __restrict__ XN8,
                                           unsigned char* lds, int rowBase, int colBase,
                                           int t, int tid) {
    unsigned char* slot = lds + (t % 3) * 16384;
    const int c = tid;                        // 16-B chunk id, 0..511
    const int row = c >> 2;
    const int scc = (c & 3) ^ ((row >> 1) & 3);   // inverse swizzle (involution)
    const unsigned char* gA = XN8 + (size_t)(rowBase + row) * KD + t * BK + scc * 16;
    const unsigned char* gB = XN8 + (size_t)(colBase + row) * KD + t * BK + scc * 16;
    __builtin_amdgcn_global_load_lds((const __attribute__((address_space(1))) void*)gA,
                                     (__attribute__((address_space(3))) void*)(slot + c * 16), 16, 0, 0);
    __builtin_amdgcn_global_load_lds((const __attribute__((address_space(1))) void*)gB,
                                     (__attribute__((address_space(3))) void*)(slot + 8192 + c * 16), 16, 0, 0);
}

#define SB __builtin_amdgcn_sched_barrier(0)
#define VMW2 asm volatile("s_waitcnt vmcnt(2)" ::: "memory"); SB
#define VMW0 asm volatile("s_waitcnt vmcnt(0)" ::: "memory"); SB
// Phase t: 6 swizzled ds_read_b128 (4 A-frag rows + 2 B-frag rows, each
// carrying kk=0|kk=1 pair) | stage tile t+2 | barrier | lgkm(0) | setprio(1)
// 16 fp8-MFMA setprio(0) | TAIL vmcnt | barrier.
// Bank math (b128, 8-lane quantum): start bank = (row&1)*16 + (l4^((row>>1)&3))*4
// -> 8 consecutive lanes hit 8 distinct 4-bank groups = conflict-free (round-7
// verified pattern).
#define PH(T, STAGE, TAILVM) do {                                              \
    unsigned char* As = lds + ((T) % 3) * 16384;                               \
    unsigned char* Bs = As + 8192;                                             \
    lx2 aV[4], bV[2];                                                          \
    _Pragma("unroll")                                                          \
    for (int m = 0; m < 4; ++m) {                                              \
        const int row = wr * 64 + m * 16 + l15;                                \
        const int cp = l4 ^ ((row >> 1) & 3);                                  \
        aV[m] = *(const lx2*)(As + row * 64 + cp * 16);                        \
    }                                                                          \
    _Pragma("unroll")                                                          \
    for (int n = 0; n < 2; ++n) {                                              \
        const int row = wc * 32 + n * 16 + l15;                                \
        const int cp = l4 ^ ((row >> 1) & 3);                                  \
        bV[n] = *(const lx2*)(Bs + row * 64 + cp * 16);                        \
    }                                                                          \
    SB;                                                                        \
    STAGE;                                                                     \
    SB;                                                                        \
    __builtin_amdgcn_s_barrier();                                              \
    asm volatile("s_waitcnt lgkmcnt(0)" ::: "memory");                         \
    SB;                                                                        \
    __builtin_amdgcn_s_setprio(1);                                             \
    _Pragma("unroll")                                                          \
    for (int kk = 0; kk < 2; ++kk)                                             \
        _Pragma("unroll")                                                      \
        for (int m = 0; m < 4; ++m)                                            \
            _Pragma("unroll")                                                  \
            for (int n = 0; n < 2; ++n)                                        \
                acc[m][n] = __builtin_amdgcn_mfma_f32_16x16x32_fp8_fp8(        \
                    aV[m][kk], bV[n][kk], acc[m][n], 0, 0, 0);                 \
    __builtin_amdgcn_s_setprio(0);                                             \
    TAILVM;                                                                    \
    __builtin_amdgcn_s_barrier();                                              \
    SB;                                                                        \
  } while (0)

// Supertile-aware triangular decode: 4x4 grid of 16x16-block supertiles.
__device__ __forceinline__ void decode_tri(int b, int& bi, int& bj) {
    const int pref[10] = {136, 392, 648, 904, 1040, 1296, 1552, 1688, 1944, 2080};
    const int sij[10]  = {0x00, 0x01, 0x02, 0x03, 0x11, 0x12, 0x13, 0x22, 0x23, 0x33};
    int st = 0;
    #pragma unroll
    for (int k = 0; k < 9; ++k) st += (b >= pref[k]);
    const int base = st ? pref[st - 1] : 0;
    const int L = b - base;
    const int si = sij[st] >> 4, sj = sij[st] & 15;
    int li, lj;
    if (si == sj) {
        li = (int)(16.5f - sqrtf(16.5f * 16.5f - 2.0f * (float)L));
        while ((li + 1) * (33 - (li + 1)) / 2 <= L) ++li;
        while (li * (33 - li) / 2 > L) --li;
        lj = li + (L - li * (33 - li) / 2);
    } else {
        li = L >> 4;
        lj = L & 15;
        if (li & 1) lj = 15 - lj;
    }
    bi = si * 16 + li;
    bj = sj * 16 + lj;
}

// Kernel 2: fp8 128x128-tile GEMM (S = XN*XN^T), 8 waves x (64x32), BK=64,
// 3-slot LDS pipeline with counted vmcnt(2); supertiled upper triangle;
// fused exp + row/col sums + pos logits.
__global__ __launch_bounds__(512, 6) void gemm_fused_kernel(const unsigned char* __restrict__ XN8,
                                                            float* __restrict__ sumexp,
                                                            float* __restrict__ poslogit) {
    __shared__ __align__(16) unsigned char lds[49152];   // 3 slots x (A 8K + B 8K)

    const int b = (blockIdx.x & 7) * (NTRI / 8) + (blockIdx.x >> 3);
    int bi, bj;
    decode_tri(b, bi, bj);

    const int rowBase = bi * TILE;
    const int colBase = bj * TILE;
    const bool offdiag = (bi != bj);

    const int tid  = threadIdx.x;
    const int lane = tid & 63;
    const int wid  = tid >> 6;          // 0..7
    const int wr   = wid >> 2;          // 0/1   (64 output rows per wave)
    const int wc   = wid & 3;           // 0..3  (32 output cols per wave)
    const int l15  = lane & 15;
    const int l4   = lane >> 4;

    f32x4 acc[4][2] = {};

    // Prologue: tiles 0,1 staged (2 loads/thread each); vmcnt(2)+barrier => t0 ready.
    stage_tile(XN8, lds, rowBase, colBase, 0, tid);
    stage_tile(XN8, lds, rowBase, colBase, 1, tid);
    VMW2;
    __builtin_amdgcn_s_barrier();

    // Main loop t=0..5: uniform counted-vmcnt phases (2 loads always in flight).
    #pragma unroll
    for (int t = 0; t < NKT - 2; ++t)
        PH(t, stage_tile(XN8, lds, rowBase, colBase, t + 2, tid), VMW2);
    // Tail: t=6 (drain t7's loads), t=7 (nothing outstanding).
    PH(NKT - 2, , VMW0);
    PH(NKT - 1, , );

    __syncthreads();   // protect LDS overlay

    // Epilogue. C/D map: col = l15, row = l4*4 + reg (shape-determined;
    // S symmetric -> transpose-safe).
    float* rowsum = (float*)lds;
    float* colsum = rowsum + TILE;
    if (tid < TILE) { rowsum[tid] = 0.0f; colsum[tid] = 0.0f; }
    __syncthreads();

    float cs[2] = {0.0f, 0.0f};
    #pragma unroll
    for (int m = 0; m < 4; ++m) {
        #pragma unroll
        for (int r = 0; r < 4; ++r) {
            const int row_l = wr * 64 + m * 16 + l4 * 4 + r;
            const int grow = rowBase + row_l;
            const int prow = grow < HALF_N ? grow + HALF_N : grow - HALF_N;
            float p = 0.0f;
            #pragma unroll
            for (int n = 0; n < 2; ++n) {
                const int gcol = colBase + wc * 32 + n * 16 + l15;
                const float s = acc[m][n][r] * TEMP_INV;
                const float e = (gcol != grow) ? __expf(s) : 0.0f;
                p += e;
                cs[n] += e;
                if (gcol == prow) {            // strictly upper triangle
                    poslogit[grow] = s;
                    poslogit[gcol] = s;        // mirrored entry (pos involution)
                }
            }
            p += __shfl_xor(p, 1);
            p += __shfl_xor(p, 2);
            p += __shfl_xor(p, 4);
            p += __shfl_xor(p, 8);
            if (l15 == 0) atomicAdd(&rowsum[row_l], p);
        }
    }
    if (offdiag) {
        #pragma unroll
        for (int n = 0; n < 2; ++n) {
            float c = cs[n];
            c += __shfl_xor(c, 16);
            c += __shfl_xor(c, 32);
            if (l4 == 0) atomicAdd(&colsum[wc * 32 + n * 16 + l15], c);
        }
    }
    __syncthreads();
    if (tid < TILE) {
        atomicAdd(&sumexp[rowBase + tid], rowsum[tid]);
        if (offdiag) atomicAdd(&sumexp[colBase + tid], colsum[tid]);
    }
}

// Kernel 3: loss = sum_i log(sumexp_i) - poslogit_i
__global__ __launch_bounds__(256) void finalize_kernel(const float* __restrict__ sumexp,
                                                       const float* __restrict__ poslogit,
                                                       float* __restrict__ out) {
    const int i = blockIdx.x * 256 + threadIdx.x;
    float li = logf(sumexp[i]) - poslogit[i];
    #pragma unroll
    for (int off = 32; off >= 1; off >>= 1) li += __shfl_xor(li, off);
    __shared__ float wss[4];
    if ((threadIdx.x & 63) == 0) wss[threadIdx.x >> 6] = li;
    __syncthreads();
    if (threadIdx.x == 0) atomicAdd(out, wss[0] + wss[1] + wss[2] + wss[3]);
}

extern "C" void kernel_launch(void* const* d_in, const int* in_sizes, int n_in,
                              void* d_out, int out_size, void* d_ws, size_t ws_size,
                              hipStream_t stream) {
    const float* X = (const float*)d_in[0];
    float* out = (float*)d_out;

    unsigned char* XN8 = (unsigned char*)d_ws;                        // 4 MB fp8 (k-paired layout)
    float* sumexp   = (float*)((char*)d_ws + (size_t)NROWS * KD);     // 32 KB
    float* poslogit = sumexp + NROWS;                                 // 32 KB

    normalize_kernel<<<NROWS, 256, 0, stream>>>(X, XN8, sumexp, out);
    gemm_fused_kernel<<<NTRI, 512, 0, stream>>>(XN8, sumexp, poslogit);
    finalize_kernel<<<NROWS / 256, 256, 0, stream>>>(sumexp, poslogit, out);
}

// Round 10
// 55.334 us; speedup vs baseline: 1.6885x; 1.0394x over previous
//
#include <hip/hip_runtime.h>
#include <hip/hip_bf16.h>
#include <math.h>

#define NROWS 8192
#define HALF_N 4096
#define KD 512
#define TILE 128
#define BK 64                     // i8: 64 B per row per K-tile
#define NKT 8                     // KD / BK
#define INV_Q2 (2.0f / 16129.0f)  // TEMP_INV / 127^2
#define NBLK 64                   // NROWS / TILE
#define NTRI 2080                 // NBLK*(NBLK+1)/2

typedef __attribute__((ext_vector_type(4))) float f32x4;
typedef __attribute__((ext_vector_type(4))) int   i32x4;

// Kernel 1: row-normalize f32 -> int8 (q = round(127*x/||x||)), zero accums.
__global__ __launch_bounds__(256) void normalize_kernel(const float* __restrict__ X,
                                                        signed char* __restrict__ XN8,
                                                        float* __restrict__ sumexp,
                                                        float* __restrict__ out) {
    const int row = blockIdx.x;
    const int tid = threadIdx.x;
    const int gz = row * 256 + tid;
    if (gz < NROWS) sumexp[gz] = 0.0f;
    if (gz == 0) out[0] = 0.0f;

    const float2 v = reinterpret_cast<const float2*>(X + (size_t)row * KD)[tid];
    float ss = v.x * v.x + v.y * v.y;
    #pragma unroll
    for (int off = 32; off >= 1; off >>= 1) ss += __shfl_xor(ss, off);
    __shared__ float wss[4];
    if ((tid & 63) == 0) wss[tid >> 6] = ss;
    __syncthreads();
    const float tot = wss[0] + wss[1] + wss[2] + wss[3];
    const float scale = 127.0f / fmaxf(sqrtf(tot), 1e-6f);
    char2 o;
    o.x = (signed char)__float2int_rn(v.x * scale);
    o.y = (signed char)__float2int_rn(v.y * scale);
    *reinterpret_cast<char2*>(XN8 + (size_t)row * KD + 2 * tid) = o;
}

#define SB __builtin_amdgcn_sched_barrier(0)
#define VMW2 asm volatile("s_waitcnt vmcnt(2)" ::: "memory"); SB
#define VMW0 asm volatile("s_waitcnt vmcnt(0)" ::: "memory"); SB

// Phase t (single-barrier): 6 swizzled ds_read_b128 (4 A-rows + 2 B-rows, each
// = full K=64 i8 fragment) | stage tile t+2 | lgkm(0) | setprio(1) 8 i8-MFMA
// setprio(0) | TAIL vmcnt | barrier.
// Ledger: reads of slot t%3 safe (tile t's loads retired by vmcnt(2)+barrier at
// end of t-1); stage writes to slot (t+2)%3=(t-1)%3 safe (every wave's t-1
// reads drained by its lgkmcnt(0) before the t-1 end barrier).
// Bank math (round-9 verified, 0 conflicts): start bank = (row&1)*16 +
// (l4^((l15>>1)&3))*4 -> 8 consecutive lanes hit 8 distinct 4-bank groups.
#define PH(T, STAGE, TAILVM) do {                                              \
    const unsigned char* As = lds + ((T) % 3) * 16384;                         \
    i32x4 aV[4], bV[2];                                                        \
    _Pragma("unroll")                                                          \
    for (int m = 0; m < 4; ++m) aV[m] = *(const i32x4*)(As + aOff[m]);         \
    _Pragma("unroll")                                                          \
    for (int n = 0; n < 2; ++n) bV[n] = *(const i32x4*)(As + 8192 + bOff[n]);  \
    SB;                                                                        \
    STAGE;                                                                     \
    SB;                                                                        \
    asm volatile("s_waitcnt lgkmcnt(0)" ::: "memory");                         \
    SB;                                                                        \
    __builtin_amdgcn_s_setprio(1);                                             \
    _Pragma("unroll")                                                          \
    for (int m = 0; m < 4; ++m)                                                \
        _Pragma("unroll")                                                      \
        for (int n = 0; n < 2; ++n)                                            \
            acc[m][n] = __builtin_amdgcn_mfma_i32_16x16x64_i8(                 \
                aV[m], bV[n], acc[m][n], 0, 0, 0);                             \
    __builtin_amdgcn_s_setprio(0);                                             \
    TAILVM;                                                                    \
    __builtin_amdgcn_s_barrier();                                              \
    SB;                                                                        \
  } while (0)

// Supertile-aware triangular decode: 4x4 grid of 16x16-block supertiles.
__device__ __forceinline__ void decode_tri(int b, int& bi, int& bj) {
    const int pref[10] = {136, 392, 648, 904, 1040, 1296, 1552, 1688, 1944, 2080};
    const int sij[10]  = {0x00, 0x01, 0x02, 0x03, 0x11, 0x12, 0x13, 0x22, 0x23, 0x33};
    int st = 0;
    #pragma unroll
    for (int k = 0; k < 9; ++k) st += (b >= pref[k]);
    const int base = st ? pref[st - 1] : 0;
    const int L = b - base;
    const int si = sij[st] >> 4, sj = sij[st] & 15;
    int li, lj;
    if (si == sj) {
        li = (int)(16.5f - sqrtf(16.5f * 16.5f - 2.0f * (float)L));
        while ((li + 1) * (33 - (li + 1)) / 2 <= L) ++li;
        while (li * (33 - li) / 2 > L) --li;
        lj = li + (L - li * (33 - li) / 2);
    } else {
        li = L >> 4;
        lj = L & 15;
        if (li & 1) lj = 15 - lj;
    }
    bi = si * 16 + li;
    bj = sj * 16 + lj;
}

// Kernel 2: int8 128x128-tile GEMM (S ~ XN*XN^T scaled by 127^2), 8 waves x
// (64x32), BK=64, 3-slot LDS pipeline, single barrier per phase, counted
// vmcnt(2); supertiled upper triangle; fused exp + row/col sums + pos logits.
__global__ __launch_bounds__(512, 6) void gemm_fused_kernel(const signed char* __restrict__ XN8,
                                                            float* __restrict__ sumexp,
                                                            float* __restrict__ poslogit) {
    __shared__ __align__(16) unsigned char lds[49152];   // 3 slots x (A 8K + B 8K)

    const int b = (blockIdx.x & 7) * (NTRI / 8) + (blockIdx.x >> 3);
    int bi, bj;
    decode_tri(b, bi, bj);

    const int rowBase = bi * TILE;
    const int colBase = bj * TILE;
    const bool offdiag = (bi != bj);

    const int tid  = threadIdx.x;
    const int lane = tid & 63;
    const int wid  = tid >> 6;          // 0..7
    const int wr   = wid >> 2;          // 0/1   (64 output rows per wave)
    const int wc   = wid & 3;           // 0..3  (32 output cols per wave)
    const int l15  = lane & 15;
    const int l4   = lane >> 4;

    // Hoisted in-slot read offsets (swizzle cp = l4 ^ ((l15>>1)&3), loop-inv).
    const int cp = l4 ^ ((l15 >> 1) & 3);
    int aOff[4], bOff[2];
    #pragma unroll
    for (int m = 0; m < 4; ++m) aOff[m] = (wr * 64 + m * 16 + l15) * 64 + cp * 16;
    #pragma unroll
    for (int n = 0; n < 2; ++n) bOff[n] = (wc * 32 + n * 16 + l15) * 64 + cp * 16;

    // Hoisted stage addressing: thread -> one A chunk + one B chunk per tile.
    const int sc   = tid;                       // 16-B chunk id, 0..511
    const int srow = sc >> 2;
    const int scc  = (sc & 3) ^ ((srow >> 1) & 3);   // inverse swizzle (involution)
    const signed char* gA0 = XN8 + (size_t)(rowBase + srow) * KD + scc * 16;
    const signed char* gB0 = XN8 + (size_t)(colBase + srow) * KD + scc * 16;
    const int ldsA = sc * 16;
    const int ldsB = 8192 + sc * 16;

#define STAGE_T(T) do {                                                          \
    unsigned char* slot = lds + ((T) % 3) * 16384;                               \
    __builtin_amdgcn_global_load_lds(                                            \
        (const __attribute__((address_space(1))) void*)(gA0 + (T) * BK),         \
        (__attribute__((address_space(3))) void*)(slot + ldsA), 16, 0, 0);       \
    __builtin_amdgcn_global_load_lds(                                            \
        (const __attribute__((address_space(1))) void*)(gB0 + (T) * BK),         \
        (__attribute__((address_space(3))) void*)(slot + ldsB), 16, 0, 0);       \
  } while (0)

    i32x4 acc[4][2] = {};

    // Prologue: tiles 0,1 staged (2 loads/thread each); vmcnt(2)+barrier => t0 ready.
    STAGE_T(0);
    STAGE_T(1);
    VMW2;
    __builtin_amdgcn_s_barrier();

    // Main loop t=0..5: uniform counted-vmcnt phases (2 loads always in flight).
    #pragma unroll
    for (int t = 0; t < NKT - 2; ++t)
        PH(t, STAGE_T(t + 2), VMW2);
    // Tail: t=6 (drain t7's loads), t=7 (nothing outstanding).
    PH(NKT - 2, , VMW0);
    PH(NKT - 1, , );

    __syncthreads();   // protect LDS overlay

    // Epilogue. C/D map: col = l15, row = l4*4 + reg (shape-determined;
    // S symmetric -> transpose-safe). logit = acc * 2/127^2.
    float* rowsum = (float*)lds;
    float* colsum = rowsum + TILE;
    if (tid < TILE) { rowsum[tid] = 0.0f; colsum[tid] = 0.0f; }
    __syncthreads();

    float cs[2] = {0.0f, 0.0f};
    #pragma unroll
    for (int m = 0; m < 4; ++m) {
        #pragma unroll
        for (int r = 0; r < 4; ++r) {
            const int row_l = wr * 64 + m * 16 + l4 * 4 + r;
            const int grow = rowBase + row_l;
            const int prow = grow < HALF_N ? grow + HALF_N : grow - HALF_N;
            float p = 0.0f;
            #pragma unroll
            for (int n = 0; n < 2; ++n) {
                const int gcol = colBase + wc * 32 + n * 16 + l15;
                const float s = (float)acc[m][n][r] * INV_Q2;
                const float e = (gcol != grow) ? __expf(s) : 0.0f;
                p += e;
                cs[n] += e;
                if (gcol == prow) {            // strictly upper triangle
                    poslogit[grow] = s;
                    poslogit[gcol] = s;        // mirrored entry (pos involution)
                }
            }
            p += __shfl_xor(p, 1);
            p += __shfl_xor(p, 2);
            p += __shfl_xor(p, 4);
            p += __shfl_xor(p, 8);
            if (l15 == 0) atomicAdd(&rowsum[row_l], p);
        }
    }
    if (offdiag) {
        #pragma unroll
        for (int n = 0; n < 2; ++n) {
            float c = cs[n];
            c += __shfl_xor(c, 16);
            c += __shfl_xor(c, 32);
            if (l4 == 0) atomicAdd(&colsum[wc * 32 + n * 16 + l15], c);
        }
    }
    __syncthreads();
    if (tid < TILE) {
        atomicAdd(&sumexp[rowBase + tid], rowsum[tid]);
        if (offdiag) atomicAdd(&sumexp[colBase + tid], colsum[tid]);
    }
#undef STAGE_T
}

// Kernel 3: loss = sum_i log(sumexp_i) - poslogit_i
__global__ __launch_bounds__(256) void finalize_kernel(const float* __restrict__ sumexp,
                                                       const float* __restrict__ poslogit,
                                                       float* __restrict__ out) {
    const int i = blockIdx.x * 256 + threadIdx.x;
    float li = logf(sumexp[i]) - poslogit[i];
    #pragma unroll
    for (int off = 32; off >= 1; off >>= 1) li += __shfl_xor(li, off);
    __shared__ float wss[4];
    if ((threadIdx.x & 63) == 0) wss[threadIdx.x >> 6] = li;
    __syncthreads();
    if (threadIdx.x == 0) atomicAdd(out, wss[0] + wss[1] + wss[2] + wss[3]);
}

extern "C" void kernel_launch(void* const* d_in, const int* in_sizes, int n_in,
                              void* d_out, int out_size, void* d_ws, size_t ws_size,
                              hipStream_t stream) {
    const float* X = (const float*)d_in[0];
    float* out = (float*)d_out;

    signed char* XN8 = (signed char*)d_ws;                            // 4 MB int8
    float* sumexp   = (float*)((char*)d_ws + (size_t)NROWS * KD);     // 32 KB
    float* poslogit = sumexp + NROWS;                                 // 32 KB

    normalize_kernel<<<NROWS, 256, 0, stream>>>(X, XN8, sumexp, out);
    gemm_fused_kernel<<<NTRI, 512, 0, stream>>>(XN8, sumexp, poslogit);
    finalize_kernel<<<NROWS / 256, 256, 0, stream>>>(sumexp, poslogit, out);
}

// Round 11
// 50.687 us; speedup vs baseline: 1.8433x; 1.0917x over previous
//
#include <hip/hip_runtime.h>
#include <hip/hip_bf16.h>
#include <math.h>

#define NROWS 8192
#define HALF_N 4096
#define KD 512
#define BM 256                    // block tile rows
#define BN 128                    // block tile cols
#define BK 64                     // i8: 64 B per row per K-tile
#define NKT 8                     // KD / BK
#define INV_Q2 (2.0f / 16129.0f)  // TEMP_INV / 127^2
#define NTILE 1056                // sum over 32 bands of (64 - 2*band)
#define SLOT 24576                // (BM+BN)*BK bytes per LDS slot

typedef __attribute__((ext_vector_type(4))) int i32x4;

// Kernel 1: row-normalize f32 -> int8 (q = round(127*x/||x||)), zero accums.
__global__ __launch_bounds__(256) void normalize_kernel(const float* __restrict__ X,
                                                        signed char* __restrict__ XN8,
                                                        float* __restrict__ sumexp,
                                                        float* __restrict__ out) {
    const int row = blockIdx.x;
    const int tid = threadIdx.x;
    const int gz = row * 256 + tid;
    if (gz < NROWS) sumexp[gz] = 0.0f;
    if (gz == 0) out[0] = 0.0f;

    const float2 v = reinterpret_cast<const float2*>(X + (size_t)row * KD)[tid];
    float ss = v.x * v.x + v.y * v.y;
    #pragma unroll
    for (int off = 32; off >= 1; off >>= 1) ss += __shfl_xor(ss, off);
    __shared__ float wss[4];
    if ((tid & 63) == 0) wss[tid >> 6] = ss;
    __syncthreads();
    const float tot = wss[0] + wss[1] + wss[2] + wss[3];
    const float scale = 127.0f / fmaxf(sqrtf(tot), 1e-6f);
    char2 o;
    o.x = (signed char)__float2int_rn(v.x * scale);
    o.y = (signed char)__float2int_rn(v.y * scale);
    *reinterpret_cast<char2*>(XN8 + (size_t)row * KD + 2 * tid) = o;
}

#define SB __builtin_amdgcn_sched_barrier(0)
#define VMW3 asm volatile("s_waitcnt vmcnt(3)" ::: "memory"); SB
#define VMW0 asm volatile("s_waitcnt vmcnt(0)" ::: "memory"); SB

// Phase t (single-barrier, round-10-verified skeleton): 8 swizzled ds_read_b128
// (4 A-rows + 4 B-rows, each a full K=64 i8 fragment) | stage tile t+2
// (3 gload_lds/thread) | lgkm(0) | setprio(1) 16 i8-MFMA setprio(0) |
// TAIL vmcnt | barrier.
// Ledger (3 loads/stage): end-of-phase vmcnt(3) => tile t+1 fully landed,
// t+2 still in flight. Bank swizzle (rounds 9-10, 0 conflicts): 16B chunk
// XOR ((row>>1)&3) on both stage-source and read side.
#define PH(T, STAGE, TAILVM) do {                                              \
    const unsigned char* As = lds + ((T) % 3) * SLOT;                          \
    i32x4 aV[4], bV[4];                                                        \
    _Pragma("unroll")                                                          \
    for (int m = 0; m < 4; ++m) aV[m] = *(const i32x4*)(As + aOff[m]);         \
    _Pragma("unroll")                                                          \
    for (int n = 0; n < 4; ++n) bV[n] = *(const i32x4*)(As + bOff[n]);         \
    SB;                                                                        \
    STAGE;                                                                     \
    SB;                                                                        \
    asm volatile("s_waitcnt lgkmcnt(0)" ::: "memory");                         \
    SB;                                                                        \
    __builtin_amdgcn_s_setprio(1);                                             \
    _Pragma("unroll")                                                          \
    for (int m = 0; m < 4; ++m)                                                \
        _Pragma("unroll")                                                      \
        for (int n = 0; n < 4; ++n)                                            \
            acc[m][n] = __builtin_amdgcn_mfma_i32_16x16x64_i8(                 \
                aV[m], bV[n], acc[m][n], 0, 0, 0);                             \
    __builtin_amdgcn_s_setprio(0);                                             \
    TAILVM;                                                                    \
    __builtin_amdgcn_s_barrier();                                              \
    SB;                                                                        \
  } while (0)

// Band decode: band i (rows 256i..) has tiles j = 2i..63 (128-col tiles).
// prefix(i) = i*(65-i); snake j-order within band for B-panel adjacency.
__device__ __forceinline__ void decode_band(int b, int& bi, int& bj) {
    int i = (int)(32.5f - sqrtf(1056.25f - (float)b));
    while ((i + 1) * (65 - (i + 1)) <= b) ++i;      // float-ulp fixup
    while (i * (65 - i) > b) --i;
    const int r = b - i * (65 - i);
    bi = i;
    bj = 2 * i + ((i & 1) ? (63 - 2 * i - r) : r);
}

// Kernel 2: int8 256x128-tile GEMM (S ~ XN*XN^T / 127^2), 8 waves x (64x64),
// BK=64, 3-slot LDS pipeline, single barrier per phase, counted vmcnt(3).
// Universal epilogue rule: count only gcol > grow, add to rowsum AND colsum
// (handles band-diagonal tiles without a diag/offdiag split).
__global__ __launch_bounds__(512, 4) void gemm_fused_kernel(const signed char* __restrict__ XN8,
                                                            float* __restrict__ sumexp,
                                                            float* __restrict__ poslogit) {
    __shared__ __align__(16) unsigned char lds[3 * SLOT];   // 72 KB -> 2 blocks/CU

    const int b = (blockIdx.x & 7) * (NTILE / 8) + (blockIdx.x >> 3);
    int bi, bj;
    decode_band(b, bi, bj);

    const int rowBase = bi * BM;
    const int colBase = bj * BN;

    const int tid  = threadIdx.x;
    const int lane = tid & 63;
    const int wid  = tid >> 6;          // 0..7
    const int wr   = wid >> 1;          // 0..3  (64 output rows per wave)
    const int wc   = wid & 1;           // 0/1   (64 output cols per wave)
    const int l15  = lane & 15;
    const int l4   = lane >> 4;

    // Hoisted in-slot read offsets (swizzle cp = l4 ^ ((l15>>1)&3); row's
    // multiple-of-16 part contributes 0 to (row>>1)&3).
    const int cp = l4 ^ ((l15 >> 1) & 3);
    int aOff[4], bOff[4];
    #pragma unroll
    for (int m = 0; m < 4; ++m) aOff[m] = (wr * 64 + m * 16 + l15) * 64 + cp * 16;
    #pragma unroll
    for (int n = 0; n < 4; ++n) bOff[n] = 16384 + (wc * 64 + n * 16 + l15) * 64 + cp * 16;

    // Hoisted stage addressing: 1536 chunks/tile (A:1024, B:512); 3 per thread.
    const int rowA0 = tid >> 2;                  // A chunk c = tid
    const int rowA1 = (tid + 512) >> 2;          // A chunk c = tid + 512
    const int rowB  = tid >> 2;                  // B chunk c = tid
    const int sccA0 = (tid & 3) ^ ((rowA0 >> 1) & 3);
    const int sccA1 = (tid & 3) ^ ((rowA1 >> 1) & 3);   // (c+512)&3 == c&3
    const signed char* gA0 = XN8 + (size_t)(rowBase + rowA0) * KD + sccA0 * 16;
    const signed char* gA1 = XN8 + (size_t)(rowBase + rowA1) * KD + sccA1 * 16;
    const signed char* gB0 = XN8 + (size_t)(colBase + rowB) * KD + sccA0 * 16;
    const int ldsA0 = tid * 16;
    const int ldsA1 = (tid + 512) * 16;
    const int ldsB  = 16384 + tid * 16;

#define STAGE_T(T) do {                                                          \
    unsigned char* slot = lds + ((T) % 3) * SLOT;                                \
    __builtin_amdgcn_global_load_lds(                                            \
        (const __attribute__((address_space(1))) void*)(gA0 + (T) * BK),         \
        (__attribute__((address_space(3))) void*)(slot + ldsA0), 16, 0, 0);      \
    __builtin_amdgcn_global_load_lds(                                            \
        (const __attribute__((address_space(1))) void*)(gA1 + (T) * BK),         \
        (__attribute__((address_space(3))) void*)(slot + ldsA1), 16, 0, 0);      \
    __builtin_amdgcn_global_load_lds(                                            \
        (const __attribute__((address_space(1))) void*)(gB0 + (T) * BK),         \
        (__attribute__((address_space(3))) void*)(slot + ldsB), 16, 0, 0);       \
  } while (0)

    i32x4 acc[4][4] = {};

    // Prologue: tiles 0,1 staged (3 loads/thread each); vmcnt(3)+barrier => t0 ready.
    STAGE_T(0);
    STAGE_T(1);
    VMW3;
    __builtin_amdgcn_s_barrier();

    // Main loop t=0..5: uniform counted-vmcnt phases (3 loads always in flight).
    #pragma unroll
    for (int t = 0; t < NKT - 2; ++t)
        PH(t, STAGE_T(t + 2), VMW3);
    // Tail: t=6 (drain t7's loads), t=7 (nothing outstanding).
    PH(NKT - 2, , VMW0);
    PH(NKT - 1, , );

    __syncthreads();   // protect LDS overlay

    // Epilogue. C/D map: col = l15, row = l4*4 + reg. logit = acc * 2/127^2.
    float* rowsum = (float*)lds;          // [256]
    float* colsum = rowsum + BM;          // [128]
    if (tid < BM) rowsum[tid] = 0.0f;
    if (tid < BN) colsum[tid] = 0.0f;
    __syncthreads();

    float cs[4] = {0.0f, 0.0f, 0.0f, 0.0f};
    #pragma unroll
    for (int m = 0; m < 4; ++m) {
        #pragma unroll
        for (int r = 0; r < 4; ++r) {
            const int row_l = wr * 64 + m * 16 + l4 * 4 + r;
            const int grow = rowBase + row_l;
            const int prow = grow < HALF_N ? grow + HALF_N : grow - HALF_N;
            float p = 0.0f;
            #pragma unroll
            for (int n = 0; n < 4; ++n) {
                const int gcol = colBase + wc * 64 + n * 16 + l15;
                const float s = (float)acc[m][n][r] * INV_Q2;
                const bool up = (gcol > grow);
                const float e = up ? __expf(s) : 0.0f;
                p += e;
                cs[n] += e;
                if (up && gcol == prow) {      // single upper occurrence
                    poslogit[grow] = s;
                    poslogit[gcol] = s;        // mirrored entry (pos involution)
                }
            }
            p += __shfl_xor(p, 1);
            p += __shfl_xor(p, 2);
            p += __shfl_xor(p, 4);
            p += __shfl_xor(p, 8);
            if (l15 == 0) atomicAdd(&rowsum[row_l], p);
        }
    }
    #pragma unroll
    for (int n = 0; n < 4; ++n) {
        float c = cs[n];
        c += __shfl_xor(c, 16);
        c += __shfl_xor(c, 32);
        if (l4 == 0) atomicAdd(&colsum[wc * 64 + n * 16 + l15], c);
    }
    __syncthreads();
    if (tid < BM) atomicAdd(&sumexp[rowBase + tid], rowsum[tid]);
    if (tid < BN) atomicAdd(&sumexp[colBase + tid], colsum[tid]);
#undef STAGE_T
}

// Kernel 3: loss = sum_i log(sumexp_i) - poslogit_i
__global__ __launch_bounds__(256) void finalize_kernel(const float* __restrict__ sumexp,
                                                       const float* __restrict__ poslogit,
                                                       float* __restrict__ out) {
    const int i = blockIdx.x * 256 + threadIdx.x;
    float li = logf(sumexp[i]) - poslogit[i];
    #pragma unroll
    for (int off = 32; off >= 1; off >>= 1) li += __shfl_xor(li, off);
    __shared__ float wss[4];
    if ((threadIdx.x & 63) == 0) wss[threadIdx.x >> 6] = li;
    __syncthreads();
    if (threadIdx.x == 0) atomicAdd(out, wss[0] + wss[1] + wss[2] + wss[3]);
}

extern "C" void kernel_launch(void* const* d_in, const int* in_sizes, int n_in,
                              void* d_out, int out_size, void* d_ws, size_t ws_size,
                              hipStream_t stream) {
    const float* X = (const float*)d_in[0];
    float* out = (float*)d_out;

    signed char* XN8 = (signed char*)d_ws;                            // 4 MB int8
    float* sumexp   = (float*)((char*)d_ws + (size_t)NROWS * KD);     // 32 KB
    float* poslogit = sumexp + NROWS;                                 // 32 KB

    normalize_kernel<<<NROWS, 256, 0, stream>>>(X, XN8, sumexp, out);
    gemm_fused_kernel<<<NTILE, 512, 0, stream>>>(XN8, sumexp, poslogit);
    finalize_kernel<<<NROWS / 256, 256, 0, stream>>>(sumexp, poslogit, out);
}